// Round 10
// baseline (320.956 us; speedup 1.0000x reference)
//
#include <hip/hip_runtime.h>
#include <hip/hip_bf16.h>

#define NN    200000
#define EE    3200000
#define DDIMC 768

#define NI4   800000    // EE/4 int4s
#define HTH   1024      // histogram block threads
#define PARTW (25 * 12 * 8192)   // legacy region size (fallback layout)

// ---- fallback (small-ws) path constants: 64KB LDS, atomic 8-copy merge ----
#define BSZC  32768
#define BSHC  15
#define NBC   7
#define CCC   72
#define DEGC  (NBC * (BSZC / 2))
#define BSZR  16384
#define BSHR  14
#define NBR   13
#define CCR   40
#define PARTC (NBR * BSZR)
#define ZLEN1   (8 * DEGC)
#define ZLEN2   (8 * PARTC)

// ---- big-ws path constants ----
// hcol (R10): u8-packed counts -> 131072 nodes per 128KB LDS bucket -> 2
// passes (was 4). Safe: per-node degree ~Poisson(16); P(deg>200) ~ 1e-90,
// so u8 (255) can't overflow, and per-block counts <= per-node degree.
#define BSZC3 131072
#define BSHC3 17
#define NBC3  2
#define CCC3  128       // 2*128 = 256 blocks, 1/CU, 128%8==0 (XCD-aligned)
// hrow: float, 32768 nodes / 128KB LDS, 7 passes (proven R9)
#define BSZR2 32768
#define BSHR2 15
#define NBR2  7
#define CCR2  32        // 7*32 = 224 blocks, 1/CU
// Big-path partial region: max(256*32768, 224*32768) words
#define BIGPART (CCR * NBR * BSZR)   // 8519680 words (covers both)

#define NDBLK 782       // ceil(NN/256)
#define XBLOCKS 1024
#define CAPL  4096

#define HB    64        // score-hist partial blocks (NN/HB = 3125 exact)
#define HW    32768     // packed u32 words (2x16-bit counts) = 65536 buckets

// ---- helpers (proven) ----
__device__ __forceinline__ float ldf(const void* p, int i, int bf) {
  if (bf) return __bfloat162float(((const __hip_bfloat16*)p)[i]);
  return ((const float*)p)[i];
}
__device__ __forceinline__ void stf(void* p, int i, float v, int bf) {
  if (bf) ((__hip_bfloat16*)p)[i] = __float2bfloat16(v);
  else ((float*)p)[i] = v;
}
__device__ __forceinline__ float bfu(unsigned u) {   // low 16 bits -> bf16 value
  return __uint_as_float(u << 16);
}
__device__ __forceinline__ float wsum(float v) {
#pragma unroll
  for (int m = 32; m >= 1; m >>= 1) v += __shfl_xor(v, m, 64);
  return v;
}
__device__ __forceinline__ int wsumi(int v) {
#pragma unroll
  for (int m = 32; m >= 1; m >>= 1) v += __shfl_xor(v, m, 64);
  return v;
}
__device__ __forceinline__ unsigned sortkey(float f) {
  unsigned u = __float_as_uint(f);
  return (u & 0x80000000u) ? ~u : (u | 0x80000000u);
}

// ---- dtype detector (proven) ----
__global__ void k_detect(const unsigned short* x16, int* flag) {
  __shared__ int cnt;
  if (threadIdx.x == 0) cnt = 0;
  __syncthreads();
  int ok = 0;
  for (int k = threadIdx.x; k < 512; k += 256) {
    unsigned short u = x16[2 * k];
    int e = (u >> 7) & 0xFF;
    if (u == 0 || (e >= 100 && e <= 150)) ok++;
  }
  atomicAdd(&cnt, ok);
  __syncthreads();
  if (threadIdx.x == 0) flag[0] = (cnt >= 400) ? 1 : 0;
}

// ================= BIG-WS PATH =============================================

// degree histogram, u8-packed: 131072 nodes / 128KB LDS, 2 passes
__global__ void __launch_bounds__(HTH) k_hcolB(const int* __restrict__ col,
                                               unsigned* __restrict__ part) {
  __shared__ unsigned lh[BSZC3 / 4];   // 32768 u32 = 128KB, 4 u8 counters each
  int t = threadIdx.x;
  int b = blockIdx.x / CCC3, j = blockIdx.x % CCC3;
  for (int k = t; k < BSZC3 / 4; k += HTH) lh[k] = 0u;
  __syncthreads();
  int base = b << BSHC3;
  const int4* c4 = (const int4*)col;
  const int stride = CCC3 * HTH;
  for (int i0 = j * HTH + t; i0 < NI4; i0 += 4 * stride) {
    int4 v[4];
#pragma unroll
    for (int u = 0; u < 4; u++) {
      int idx = i0 + u * stride;
      if (idx < NI4) v[u] = c4[idx];
      else { v[u].x = -1; v[u].y = -1; v[u].z = -1; v[u].w = -1; }  // sentinel
    }
#pragma unroll
    for (int u = 0; u < 4; u++) {
      int a0 = v[u].x - base, a1 = v[u].y - base, a2 = v[u].z - base, a3 = v[u].w - base;
      if ((unsigned)a0 < (unsigned)BSZC3) atomicAdd(&lh[a0 >> 2], 1u << ((a0 & 3) * 8));
      if ((unsigned)a1 < (unsigned)BSZC3) atomicAdd(&lh[a1 >> 2], 1u << ((a1 & 3) * 8));
      if ((unsigned)a2 < (unsigned)BSZC3) atomicAdd(&lh[a2 >> 2], 1u << ((a2 & 3) * 8));
      if ((unsigned)a3 < (unsigned)BSZC3) atomicAdd(&lh[a3 >> 2], 1u << ((a3 & 3) * 8));
    }
  }
  __syncthreads();
  unsigned* dst = part + (size_t)blockIdx.x * (BSZC3 / 4);
  for (int k = 4 * t; k < BSZC3 / 4; k += 4 * HTH)
    *(uint4*)&dst[k] = *(const uint4*)&lh[k];
}

__global__ void k_redAB(const unsigned* __restrict__ part, float* __restrict__ dis,
                        const void* docf, const void* dw, const void* db,
                        float* __restrict__ d, const int* flagp) {
  if (blockIdx.x < NDBLK) {
    int i = blockIdx.x * 256 + threadIdx.x;
    if (i < NN) {
      int b = i >> BSHC3;
      int w = i & (BSZC3 - 1);
      int sh = (w & 3) * 8;
      const unsigned* p = part + (size_t)b * CCC3 * (BSZC3 / 4) + (w >> 2);
      int deg = 1;
#pragma unroll 8
      for (int j = 0; j < CCC3; j++)
        deg += (int)((p[(size_t)j * (BSZC3 / 4)] >> sh) & 255u);
      dis[i] = rsqrtf((float)deg);
    }
  } else {
    int flag = flagp[0];
    int o = (blockIdx.x - NDBLK) * 4 + (threadIdx.x >> 6);
    int lane = threadIdx.x & 63;
    float acc = 0.f;
    for (int k = lane; k < DDIMC; k += 64) acc += ldf(docf, k, flag) * ldf(dw, o * DDIMC + k, flag);
    acc = wsum(acc);
    if (lane == 0) d[o] = fmaxf(acc + ldf(db, o, flag), 0.0f);
  }
}

__global__ void __launch_bounds__(HTH) k_hrowB(const int* __restrict__ row, const int* __restrict__ col,
                                               const float* __restrict__ dis,
                                               float* __restrict__ part) {
  __shared__ float lh[BSZR2];          // 128KB
  int t = threadIdx.x;
  int b = blockIdx.x / CCR2, j = blockIdx.x % CCR2;
  for (int k = t; k < BSZR2; k += HTH) lh[k] = 0.f;
  __syncthreads();
  int base = b << BSHR2;
  const int4* r4 = (const int4*)row;
  const int4* c4 = (const int4*)col;
  const int stride = CCR2 * HTH;
  for (int i0 = j * HTH + t; i0 < NI4; i0 += 4 * stride) {
    int4 r[4], c[4];
#pragma unroll
    for (int u = 0; u < 4; u++) {
      int idx = i0 + u * stride;
      if (idx < NI4) { r[u] = r4[idx]; c[u] = c4[idx]; }
      else { r[u].x = -1; r[u].y = -1; r[u].z = -1; r[u].w = -1;    // sentinel
             c[u].x = 0;  c[u].y = 0;  c[u].z = 0;  c[u].w = 0; }
    }
#pragma unroll
    for (int u = 0; u < 4; u++) {
      int a0 = r[u].x - base, a1 = r[u].y - base, a2 = r[u].z - base, a3 = r[u].w - base;
      if ((unsigned)a0 < (unsigned)BSZR2) atomicAdd(&lh[a0], dis[c[u].x]);
      if ((unsigned)a1 < (unsigned)BSZR2) atomicAdd(&lh[a1], dis[c[u].y]);
      if ((unsigned)a2 < (unsigned)BSZR2) atomicAdd(&lh[a2], dis[c[u].z]);
      if ((unsigned)a3 < (unsigned)BSZR2) atomicAdd(&lh[a3], dis[c[u].w]);
    }
  }
  __syncthreads();
  float* dst = part + (size_t)blockIdx.x * BSZR2;
  for (int k = 4 * t; k < BSZR2; k += 4 * HTH)
    *(float4*)&dst[k] = *(const float4*)&lh[k];
}

__global__ void k_redBB(const float* __restrict__ part, const float* __restrict__ dis,
                        float* __restrict__ c) {
  int i = blockIdx.x * 256 + threadIdx.x;
  if (i < NN) {
    int b = i >> BSHR2;
    int k = i & (BSZR2 - 1);
    const float* p = part + (size_t)b * CCR2 * BSZR2 + k;
    float s = 0.f;
#pragma unroll 8
    for (int j = 0; j < CCR2; j++) s += p[(size_t)j * BSZR2];
    float dv = dis[i];
    c[i] = dv * s + dv * dv;
  }
}

// ================= FALLBACK PATH (proven): 64KB LDS, atomic 8-copy merge ====
__global__ void __launch_bounds__(HTH) k_hcol(const int* __restrict__ col,
                                              unsigned* __restrict__ degm) {
  __shared__ unsigned lh[BSZC / 2];
  int t = threadIdx.x;
  int b = blockIdx.x / CCC, j = blockIdx.x % CCC;
  for (int k = t; k < BSZC / 2; k += HTH) lh[k] = 0u;
  __syncthreads();
  int base = b << BSHC;
  const int4* c4 = (const int4*)col;
  const int stride = CCC * HTH;
  for (int i = j * HTH + t; i < NI4; i += 2 * stride) {
    int4 v0 = c4[i];
    int i2 = i + stride;
    int4 v1; v1.x = v1.y = v1.z = v1.w = -1;
    if (i2 < NI4) v1 = c4[i2];
    {
      int a0 = v0.x - base, a1 = v0.y - base, a2 = v0.z - base, a3 = v0.w - base;
      if ((unsigned)a0 < (unsigned)BSZC) atomicAdd(&lh[a0 >> 1], 1u << ((a0 & 1) * 16));
      if ((unsigned)a1 < (unsigned)BSZC) atomicAdd(&lh[a1 >> 1], 1u << ((a1 & 1) * 16));
      if ((unsigned)a2 < (unsigned)BSZC) atomicAdd(&lh[a2 >> 1], 1u << ((a2 & 1) * 16));
      if ((unsigned)a3 < (unsigned)BSZC) atomicAdd(&lh[a3 >> 1], 1u << ((a3 & 1) * 16));
    }
    {
      int a0 = v1.x - base, a1 = v1.y - base, a2 = v1.z - base, a3 = v1.w - base;
      if ((unsigned)a0 < (unsigned)BSZC) atomicAdd(&lh[a0 >> 1], 1u << ((a0 & 1) * 16));
      if ((unsigned)a1 < (unsigned)BSZC) atomicAdd(&lh[a1 >> 1], 1u << ((a1 & 1) * 16));
      if ((unsigned)a2 < (unsigned)BSZC) atomicAdd(&lh[a2 >> 1], 1u << ((a2 & 1) * 16));
      if ((unsigned)a3 < (unsigned)BSZC) atomicAdd(&lh[a3 >> 1], 1u << ((a3 & 1) * 16));
    }
  }
  __syncthreads();
  unsigned* dst = degm + (size_t)(j & 7) * DEGC + (size_t)b * (BSZC / 2);
  for (int k = t; k < BSZC / 2; k += HTH) {
    unsigned v = lh[k];
    if (v) atomicAdd(&dst[k], v);
  }
}

__global__ void k_redA(const unsigned* __restrict__ degm, float* __restrict__ dis,
                       const void* docf, const void* dw, const void* db,
                       float* __restrict__ d, const int* flagp) {
  if (blockIdx.x < NDBLK) {
    int i = blockIdx.x * 256 + threadIdx.x;
    if (i < NN) {
      int sh = (i & 1) * 16;
      int deg = 1;
#pragma unroll
      for (int p = 0; p < 8; p++) {
        unsigned w_ = degm[(size_t)p * DEGC + (i >> 1)];
        deg += (int)((w_ >> sh) & 0xffffu);
      }
      dis[i] = rsqrtf((float)deg);
    }
  } else {
    int flag = flagp[0];
    int o = (blockIdx.x - NDBLK) * 4 + (threadIdx.x >> 6);
    int lane = threadIdx.x & 63;
    float acc = 0.f;
    for (int k = lane; k < DDIMC; k += 64) acc += ldf(docf, k, flag) * ldf(dw, o * DDIMC + k, flag);
    acc = wsum(acc);
    if (lane == 0) d[o] = fmaxf(acc + ldf(db, o, flag), 0.0f);
  }
}

__global__ void __launch_bounds__(HTH) k_hrow(const int* __restrict__ row, const int* __restrict__ col,
                                              const float* __restrict__ dis,
                                              float* __restrict__ partm) {
  __shared__ float lh[BSZR];
  int t = threadIdx.x;
  int b = blockIdx.x / CCR, j = blockIdx.x % CCR;
  for (int k = t; k < BSZR; k += HTH) lh[k] = 0.f;
  __syncthreads();
  int base = b << BSHR;
  const int4* r4 = (const int4*)row;
  const int4* c4 = (const int4*)col;
  const int stride = CCR * HTH;
  for (int i = j * HTH + t; i < NI4; i += 2 * stride) {
    int4 r0 = r4[i];
    int4 c0 = c4[i];
    int i2 = i + stride;
    int4 r1; r1.x = r1.y = r1.z = r1.w = -1;
    int4 c1; c1.x = c1.y = c1.z = c1.w = 0;
    if (i2 < NI4) { r1 = r4[i2]; c1 = c4[i2]; }
    {
      int a0 = r0.x - base, a1 = r0.y - base, a2 = r0.z - base, a3 = r0.w - base;
      if ((unsigned)a0 < (unsigned)BSZR) atomicAdd(&lh[a0], dis[c0.x]);
      if ((unsigned)a1 < (unsigned)BSZR) atomicAdd(&lh[a1], dis[c0.y]);
      if ((unsigned)a2 < (unsigned)BSZR) atomicAdd(&lh[a2], dis[c0.z]);
      if ((unsigned)a3 < (unsigned)BSZR) atomicAdd(&lh[a3], dis[c0.w]);
    }
    {
      int a0 = r1.x - base, a1 = r1.y - base, a2 = r1.z - base, a3 = r1.w - base;
      if ((unsigned)a0 < (unsigned)BSZR) atomicAdd(&lh[a0], dis[c1.x]);
      if ((unsigned)a1 < (unsigned)BSZR) atomicAdd(&lh[a1], dis[c1.y]);
      if ((unsigned)a2 < (unsigned)BSZR) atomicAdd(&lh[a2], dis[c1.z]);
      if ((unsigned)a3 < (unsigned)BSZR) atomicAdd(&lh[a3], dis[c1.w]);
    }
  }
  __syncthreads();
  float* dst = partm + (size_t)(j & 7) * PARTC + (size_t)b * BSZR;
  for (int k = t; k < BSZR; k += HTH) {
    float v = lh[k];
    if (v != 0.f) atomicAdd(&dst[k], v);
  }
}

__global__ void k_redB(const float* __restrict__ partm, const float* __restrict__ dis,
                       float* __restrict__ c) {
  int i = blockIdx.x * 256 + threadIdx.x;
  if (i < NN) {
    float s = 0.f;
#pragma unroll
    for (int p = 0; p < 8; p++) s += partm[(size_t)p * PARTC + i];
    float dv = dis[i];
    c[i] = dv * s + dv * dv;
  }
}

// ---- fused x pass (proven R2): pure stream, score + column accumulator ----
__global__ void k_x(const void* x, const void* pw, const float* __restrict__ c,
                    float* __restrict__ score,
                    float* __restrict__ s8, const int* flagp) {
  __shared__ float sred[4][64];
  int flag = flagp[0];
  int t = threadIdx.x;
  int lane = t & 63;
  int w = t >> 6;
  int wid = (blockIdx.x * 256 + t) >> 6;
  int nw = (gridDim.x * 256) >> 6;

  if (flag) {
    int g  = lane >> 3;
    int c0 = (lane & 7) * 8;
    float pwv[8];
#pragma unroll
    for (int j = 0; j < 8; j++) pwv[j] = ldf(pw, c0 + j, 1);
    float s = 0.f;
#pragma unroll
    for (int j = 0; j < 8; j++) s += pwv[j] * pwv[j];
    float inv = 1.0f / sqrtf(wsum(s) * 0.125f);
    float sacc[8] = {0.f, 0.f, 0.f, 0.f, 0.f, 0.f, 0.f, 0.f};
    const uint4* x4 = (const uint4*)x;
    for (int r0 = wid * 8; r0 < NN; r0 += nw * 8) {
      int r = r0 + g;
      uint4 u = x4[r * 8 + (lane & 7)];
      float xv[8] = { bfu(u.x & 0xffff), bfu(u.x >> 16),
                      bfu(u.y & 0xffff), bfu(u.y >> 16),
                      bfu(u.z & 0xffff), bfu(u.z >> 16),
                      bfu(u.w & 0xffff), bfu(u.w >> 16) };
      float dot = 0.f;
#pragma unroll
      for (int j = 0; j < 8; j++) dot += xv[j] * pwv[j];
      dot += __shfl_xor(dot, 1, 64);
      dot += __shfl_xor(dot, 2, 64);
      dot += __shfl_xor(dot, 4, 64);
      float cr = c[r];
#pragma unroll
      for (int j = 0; j < 8; j++) sacc[j] += cr * xv[j];
      if ((lane & 7) == 0) score[r] = dot * inv;
    }
#pragma unroll
    for (int j = 0; j < 8; j++) {
      sacc[j] += __shfl_xor(sacc[j], 8, 64);
      sacc[j] += __shfl_xor(sacc[j], 16, 64);
      sacc[j] += __shfl_xor(sacc[j], 32, 64);
    }
    if (lane < 8) {
#pragma unroll
      for (int j = 0; j < 8; j++) sred[w][lane * 8 + j] = sacc[j];
    }
  } else {
    int g  = lane >> 4;
    int c0 = (lane & 15) * 4;
    float pwv[4];
#pragma unroll
    for (int j = 0; j < 4; j++) pwv[j] = ((const float*)pw)[c0 + j];
    float s = 0.f;
#pragma unroll
    for (int j = 0; j < 4; j++) s += pwv[j] * pwv[j];
    float inv = 1.0f / sqrtf(wsum(s) * (1.f / 16.f));
    float sacc[4] = {0.f, 0.f, 0.f, 0.f};
    const float4* x4 = (const float4*)x;
    for (int r0 = wid * 4; r0 < NN; r0 += nw * 4) {
      int r = r0 + g;
      float4 v = x4[r * 16 + (lane & 15)];
      float xv[4] = { v.x, v.y, v.z, v.w };
      float dot = 0.f;
#pragma unroll
      for (int j = 0; j < 4; j++) dot += xv[j] * pwv[j];
      dot += __shfl_xor(dot, 1, 64);
      dot += __shfl_xor(dot, 2, 64);
      dot += __shfl_xor(dot, 4, 64);
      dot += __shfl_xor(dot, 8, 64);
      float cr = c[r];
#pragma unroll
      for (int j = 0; j < 4; j++) sacc[j] += cr * xv[j];
      if ((lane & 15) == 0) score[r] = dot * inv;
    }
#pragma unroll
    for (int j = 0; j < 4; j++) {
      sacc[j] += __shfl_xor(sacc[j], 16, 64);
      sacc[j] += __shfl_xor(sacc[j], 32, 64);
    }
    if (lane < 16) {
#pragma unroll
      for (int j = 0; j < 4; j++) sred[w][lane * 4 + j] = sacc[j];
    }
  }
  __syncthreads();
  if (w == 0)
    atomicAdd(&s8[(blockIdx.x & 7) * 64 + lane],
              sred[0][lane] + sred[1][lane] + sred[2][lane] + sred[3][lane]);
}

// ---- LDS-privatized full-resolution score histogram (proven R2) ----
__global__ void __launch_bounds__(1024) k_hist(const float* __restrict__ score,
                                               unsigned* __restrict__ part) {
  __shared__ unsigned lh[HW];
  int t = threadIdx.x;
  for (int k = t; k < HW; k += 1024) lh[k] = 0u;
  __syncthreads();
  int r0 = blockIdx.x * (NN / HB);
  int r1 = r0 + (NN / HB);
  for (int i = r0 + t; i < r1; i += 1024) {
    unsigned b = sortkey(score[i]) >> 16;
    atomicAdd(&lh[b >> 1], 1u << ((b & 1) * 16));
  }
  __syncthreads();
  unsigned* dst = part + (size_t)blockIdx.x * HW;
  for (int k = t; k < HW; k += 1024) dst[k] = lh[k];
}

// ---- sum HB packed partials -> hist (proven R2) ----
__global__ void k_redH(const unsigned* __restrict__ part, int* __restrict__ hist) {
  int w = blockIdx.x * 256 + threadIdx.x;
  unsigned lo = 0, hi = 0;
  for (int b = 0; b < HB; b++) {
    unsigned v = part[(size_t)b * HW + w];
    lo += v & 0xffffu;
    hi += v >> 16;
  }
  hist[2 * w]     = (int)lo;
  hist[2 * w + 1] = (int)hi;
}

// ---- threshold (proven) ----
__global__ void k_thresh(const int* __restrict__ hist, int* __restrict__ thrB,
                         const float* __restrict__ s8, float* __restrict__ svec) {
  __shared__ int part[256];
  __shared__ int segl[256];
  __shared__ int res2[2];
  int t = threadIdx.x, w = t >> 6, lane = t & 63;
  if (t < 64) {
    float a = 0.f;
    for (int r = 0; r < 8; r++) a += s8[r * 64 + t];
    svec[t] = a;
  }
  for (int m = w; m < 256; m += 4) {
    const int* hb = &hist[m * 256];
    int a = hb[lane] + hb[lane + 64] + hb[lane + 128] + hb[lane + 192];
    a = wsumi(a);
    if (lane == 0) part[m] = a;
  }
  __syncthreads();
  if (t == 0) {
    int acc = 0, seg = 0, above = 0;
    for (int b = 255; b >= 0; b--) {
      if (acc + part[b] >= 64) { seg = b; above = acc; break; }
      acc += part[b];
    }
    res2[0] = seg; res2[1] = above;
  }
  __syncthreads();
  segl[t] = hist[res2[0] * 256 + t];
  __syncthreads();
  if (t == 0) {
    int acc = res2[1], B = res2[0] * 256;
    for (int j = 255; j >= 0; j--) {
      acc += segl[j];
      if (acc >= 64) { B = res2[0] * 256 + j; break; }
    }
    thrB[0] = B;
  }
}

// ---- collect (proven) ----
__global__ void k_collect(const float* __restrict__ score, const int* __restrict__ thrB,
                          int* __restrict__ candn, unsigned* __restrict__ ckey,
                          int* __restrict__ cidx) {
  int i = blockIdx.x * blockDim.x + threadIdx.x;
  if (i >= NN) return;
  unsigned u = sortkey(score[i]);
  if ((int)(u >> 16) >= thrB[0]) {
    int p = atomicAdd(candn, 1);
    if (p < CAPL) { ckey[p] = u; cidx[p] = i; }
  }
}

// ---- top-64 (1024 threads, proven) ----
__global__ void __launch_bounds__(1024) k_top(const int* __restrict__ candn,
                      const unsigned* __restrict__ ckey,
                      const int* __restrict__ cidx, const void* x,
                      float* __restrict__ xt, const int* flagp) {
  __shared__ unsigned long long keys[CAPL];
  __shared__ int perm[64];
  __shared__ float ts[64];
  int flag = flagp[0];
  int t = threadIdx.x;
  int M = candn[0];
  if (M > CAPL) M = CAPL;
  for (int j = t; j < M; j += 1024)
    keys[j] = (((unsigned long long)ckey[j]) << 32) |
              (unsigned long long)(0xFFFFFFFFu - (unsigned)cidx[j]);
  __syncthreads();
  for (int j = t; j < M; j += 1024) {
    unsigned long long k = keys[j];
    int rank = 0;
    for (int i = 0; i < M; i++) rank += (keys[i] > k) ? 1 : 0;
    if (rank < 64) {
      unsigned ku = (unsigned)(k >> 32);
      unsigned idx = 0xFFFFFFFFu - (unsigned)(k & 0xFFFFFFFFu);
      perm[rank] = (int)idx;
      unsigned bits = (ku & 0x80000000u) ? (ku ^ 0x80000000u) : ~ku;
      ts[rank] = tanhf(__uint_as_float(bits));
    }
  }
  __syncthreads();
  for (int q = t; q < 4096; q += 1024) {
    int j = q >> 6, f = q & 63;
    xt[q] = ldf(x, perm[j] * 64 + f, flag) * ts[j];
  }
}

// ---- GRU (proven round-0 rework): coalesced staging, LDS-side transpose ----
#define GS 193
__device__ __forceinline__ void stage_w(const void* src, float* dst, int flag, int t) {
  if (flag) {
    const uint4* s4 = (const uint4*)src;
    for (int k = t; k < 1536; k += 256) {
      uint4 u = s4[k];
      int e = k << 3; int o = e >> 6, f = e & 63;
      float* d_ = &dst[f * GS + o];
      d_[0]      = bfu(u.x & 0xffff); d_[GS]     = bfu(u.x >> 16);
      d_[2 * GS] = bfu(u.y & 0xffff); d_[3 * GS] = bfu(u.y >> 16);
      d_[4 * GS] = bfu(u.z & 0xffff); d_[5 * GS] = bfu(u.z >> 16);
      d_[6 * GS] = bfu(u.w & 0xffff); d_[7 * GS] = bfu(u.w >> 16);
    }
  } else {
    const float4* s4 = (const float4*)src;
    for (int k = t; k < 3072; k += 256) {
      float4 v = s4[k];
      int e = k << 2; int o = e >> 6, f = e & 63;
      float* d_ = &dst[f * GS + o];
      d_[0] = v.x; d_[GS] = v.y; d_[2 * GS] = v.z; d_[3 * GS] = v.w;
    }
  }
}

__global__ void k_gru(const float* __restrict__ xt, const void* h0g, const void* wihg,
                      const void* whhg, const void* bihg, const void* bhhg,
                      float* __restrict__ Wout, const int* flagp) {
  __shared__ float wb1[64 * GS];
  __shared__ float wb2[64 * GS];
  __shared__ float xtr[256];
  __shared__ float h0r[256];
  int flag = flagp[0];
  int t = threadIdx.x;
  int j0 = blockIdx.x * 4;
  { int jj = t >> 6, f = t & 63;
    xtr[t] = xt[(j0 + jj) * 64 + f];
    h0r[t] = ldf(h0g, (j0 + jj) * 64 + f, flag); }
  stage_w(wihg, wb1, flag, t);
  stage_w(whhg, wb2, flag, t);
  __syncthreads();
  int jl = t >> 6, c2 = t & 63;
  float xr = 0, xz = 0, xn = 0, hr = 0, hz = 0, hn = 0;
#pragma unroll 4
  for (int f = 0; f < 64; f++) {
    float xv = xtr[jl * 64 + f];
    float hv = h0r[jl * 64 + f];
    const float* w1 = &wb1[f * GS];
    const float* w2 = &wb2[f * GS];
    xr += xv * w1[c2]; xz += xv * w1[64 + c2]; xn += xv * w1[128 + c2];
    hr += hv * w2[c2]; hz += hv * w2[64 + c2]; hn += hv * w2[128 + c2];
  }
  xr += ldf(bihg, c2, flag); xz += ldf(bihg, 64 + c2, flag); xn += ldf(bihg, 128 + c2, flag);
  hr += ldf(bhhg, c2, flag); hz += ldf(bhhg, 64 + c2, flag); hn += ldf(bhhg, 128 + c2, flag);
  float rg = 1.f / (1.f + expf(-(xr + hr)));
  float zg = 1.f / (1.f + expf(-(xz + hz)));
  float nc = tanhf(xn + rg * hn);
  Wout[(j0 + jl) * 64 + c2] = (1.f - zg) * nc + zg * h0r[jl * 64 + c2];
}

// ---- FUSED tail (R10): g + layernorm + fusion-FC + heads in ONE block ----
// These were 4 dispatches totaling ~150K MACs -- pure launch overhead.
// Single 1024-thread block; all intermediates LDS-resident.
__global__ void __launch_bounds__(1024) k_tail(
    const float* __restrict__ svec, const float* __restrict__ Wm,
    const void* gw, const void* gb, const float* __restrict__ dvec,
    const void* lng, const void* lnb, const void* fw, const void* fb,
    const void* tw, const void* tb, const void* tmw, const void* tmb,
    void* out, const int* flagp) {
  __shared__ float svl[64], pooled[64], gl[256], lnv[512], h1l[256];
  __shared__ float red[512];
  __shared__ float stats[2];
  int flag = flagp[0];
  int t = threadIdx.x;
  // phase 1: pooled = (svec @ W) / NN
  if (t < 64) svl[t] = svec[t];
  __syncthreads();
  if (t < 64) {
    float a = 0.f;
    for (int f = 0; f < 64; f++) a += svl[f] * Wm[f * 64 + t];   // coalesced
    pooled[t] = a * (1.0f / (float)NN);
  }
  __syncthreads();
  // phase 2: g[o] = pooled @ gw.T + gb  (4 lanes per output)
  {
    int o = t >> 2, li = t & 3;
    float acc = 0.f;
    for (int kk = 0; kk < 16; kk++) {
      int l = li * 16 + kk;
      acc += pooled[l] * ldf(gw, o * 64 + l, flag);
    }
    acc += __shfl_xor(acc, 1, 64);
    acc += __shfl_xor(acc, 2, 64);
    if (li == 0) gl[o] = acc + ldf(gb, o, flag);
  }
  __syncthreads();
  // phase 3: layernorm over [g | d]
  float val = 0.f;
  if (t < 256) val = gl[t];
  else if (t < 512) val = dvec[t - 256];
  if (t < 512) red[t] = val;
  __syncthreads();
  for (int s = 256; s > 0; s >>= 1) { if (t < s) red[t] += red[t + s]; __syncthreads(); }
  if (t == 0) stats[0] = red[0];
  __syncthreads();
  if (t < 512) red[t] = val * val;
  __syncthreads();
  for (int s = 256; s > 0; s >>= 1) { if (t < s) red[t] += red[t + s]; __syncthreads(); }
  if (t == 0) stats[1] = red[0];
  __syncthreads();
  float mu = stats[0] * (1.f / 512.f);
  float var = stats[1] * (1.f / 512.f) - mu * mu;
  float istd = rsqrtf(var + 1e-5f);
  if (t < 512) lnv[t] = (val - mu) * istd * ldf(lng, t, flag) + ldf(lnb, t, flag);
  __syncthreads();
  // phase 4: h1 = relu(lnv @ fw.T + fb)  (4 lanes per output, vector loads)
  {
    int o = t >> 2, li = t & 3;
    float acc = 0.f;
    if (flag) {
      const uint4* fr = (const uint4*)((const unsigned short*)fw + o * 512) + li * 16;
      for (int kk = 0; kk < 16; kk++) {
        uint4 u = fr[kk];
        const float* l = &lnv[li * 128 + kk * 8];
        acc += bfu(u.x & 0xffff) * l[0] + bfu(u.x >> 16) * l[1]
             + bfu(u.y & 0xffff) * l[2] + bfu(u.y >> 16) * l[3]
             + bfu(u.z & 0xffff) * l[4] + bfu(u.z >> 16) * l[5]
             + bfu(u.w & 0xffff) * l[6] + bfu(u.w >> 16) * l[7];
      }
    } else {
      const float4* fr = (const float4*)((const float*)fw + o * 512) + li * 32;
      for (int kk = 0; kk < 32; kk++) {
        float4 v = fr[kk];
        const float* l = &lnv[li * 128 + kk * 4];
        acc += v.x * l[0] + v.y * l[1] + v.z * l[2] + v.w * l[3];
      }
    }
    acc += __shfl_xor(acc, 1, 64);
    acc += __shfl_xor(acc, 2, 64);
    if (li == 0) h1l[o] = fmaxf(acc + ldf(fb, o, flag), 0.0f);
  }
  __syncthreads();
  // phase 5: task + time heads (17 outputs, wave each; wave 0 does 2)
  {
    int lane = t & 63;
    for (int o = t >> 6; o < 17; o += 16) {
      float acc = 0.f;
      if (o < 16) { for (int k = lane; k < 256; k += 64) acc += h1l[k] * ldf(tw, o * 256 + k, flag); }
      else        { for (int k = lane; k < 256; k += 64) acc += h1l[k] * ldf(tmw, k, flag); }
      acc = wsum(acc);
      if (lane == 0) {
        float bias = (o < 16) ? ldf(tb, o, flag) : ldf(tmb, 0, flag);
        stf(out, o, acc + bias, flag);
      }
    }
  }
}

extern "C" void kernel_launch(void* const* d_in, const int* in_sizes, int n_in,
                              void* d_out, int out_size, void* d_ws, size_t ws_size,
                              hipStream_t stream) {
  const void* x    = d_in[0];
  const int*  ei   = (const int*)d_in[1];
  const void* docf = d_in[2];
  const void* pw   = d_in[3];
  const void* h0   = d_in[4];
  const void* wih  = d_in[5];
  const void* whh  = d_in[6];
  const void* bih  = d_in[7];
  const void* bhh  = d_in[8];
  const void* gw   = d_in[9];
  const void* gb   = d_in[10];
  const void* dw   = d_in[11];
  const void* db   = d_in[12];
  const void* lng  = d_in[13];
  const void* lnb  = d_in[14];
  const void* fw   = d_in[15];
  const void* fb   = d_in[16];
  const void* tw   = d_in[17];
  const void* tb   = d_in[18];
  const void* tmw  = d_in[19];
  const void* tmb  = d_in[20];

  const int* row = ei;
  const int* col = ei + EE;

  float* wsf = (float*)d_ws;
  int*   wsi = (int*)d_ws;

  int big = (ws_size >= (size_t)42 * 1024 * 1024);
  size_t base = big ? (size_t)BIGPART : (size_t)PARTW;

  size_t oHIST  = base;
  size_t oCANDN = oHIST + 65536;
  size_t oS8    = oCANDN + 8;
  size_t oFLAG  = oS8 + 512;
  size_t oTHR   = oFLAG + 8;
  size_t oSV    = oTHR + 8;
  size_t oD     = oSV + 64;
  size_t oDIS   = oD + 256;
  size_t oC     = oDIS + NN;
  size_t oSCORE = oC + NN;
  size_t oCKEY  = oSCORE + NN;
  size_t oCIDX  = oCKEY + 4096;
  size_t oXT    = oCIDX + 4096;
  size_t oWW    = oXT + 4096;

  hipMemsetAsync(wsi + oCANDN, 0, (size_t)(8 + 512) * 4, stream);
  k_detect<<<1, 256, 0, stream>>>((const unsigned short*)x, wsi + oFLAG);

  if (big) {
    k_hcolB<<<NBC3 * CCC3, HTH, 0, stream>>>(col, (unsigned*)wsi);
    k_redAB<<<NDBLK + 64, 256, 0, stream>>>((const unsigned*)wsi, wsf + oDIS,
                                            docf, dw, db, wsf + oD, wsi + oFLAG);
    k_hrowB<<<NBR2 * CCR2, HTH, 0, stream>>>(row, col, wsf + oDIS, wsf);
    k_redBB<<<NDBLK, 256, 0, stream>>>(wsf, wsf + oDIS, wsf + oC);
  } else {
    hipMemsetAsync(wsi, 0, (size_t)ZLEN1 * 4, stream);
    k_hcol<<<NBC * CCC, HTH, 0, stream>>>(col, (unsigned*)wsi);
    k_redA<<<NDBLK + 64, 256, 0, stream>>>((const unsigned*)wsi, wsf + oDIS,
                                           docf, dw, db, wsf + oD, wsi + oFLAG);
    hipMemsetAsync(wsi, 0, (size_t)ZLEN2 * 4, stream);
    k_hrow<<<NBR * CCR, HTH, 0, stream>>>(row, col, wsf + oDIS, wsf);
    k_redB<<<NDBLK, 256, 0, stream>>>(wsf, wsf + oDIS, wsf + oC);
  }

  k_x<<<XBLOCKS, 256, 0, stream>>>(x, pw, wsf + oC, wsf + oSCORE,
                                   wsf + oS8, wsi + oFLAG);
  k_hist<<<HB, 1024, 0, stream>>>(wsf + oSCORE, (unsigned*)wsi);
  k_redH<<<HW / 256, 256, 0, stream>>>((const unsigned*)wsi, wsi + oHIST);
  k_thresh<<<1, 256, 0, stream>>>(wsi + oHIST, wsi + oTHR, wsf + oS8, wsf + oSV);
  k_collect<<<NDBLK, 256, 0, stream>>>(wsf + oSCORE, wsi + oTHR, wsi + oCANDN,
                                       (unsigned*)(wsi + oCKEY), wsi + oCIDX);
  k_top<<<1, 1024, 0, stream>>>(wsi + oCANDN, (const unsigned*)(wsi + oCKEY),
                                wsi + oCIDX, x, wsf + oXT, wsi + oFLAG);
  k_gru<<<16, 256, 0, stream>>>(wsf + oXT, h0, wih, whh, bih, bhh, wsf + oWW, wsi + oFLAG);
  k_tail<<<1, 1024, 0, stream>>>(wsf + oSV, wsf + oWW, gw, gb, wsf + oD,
                                 lng, lnb, fw, fb, tw, tb, tmw, tmb,
                                 d_out, wsi + oFLAG);
}

// Round 11
// 297.349 us; speedup vs baseline: 1.0794x; 1.0794x over previous
//
#include <hip/hip_runtime.h>
#include <hip/hip_bf16.h>

#define NN    200000
#define EE    3200000
#define DDIMC 768

#define NI4   800000    // EE/4 int4s
#define HTH   1024      // histogram block threads
#define PARTW (25 * 12 * 8192)   // legacy region size (fallback layout)

// ---- fallback (small-ws) path constants: 64KB LDS, atomic 8-copy merge ----
#define BSZC  32768
#define BSHC  15
#define NBC   7
#define CCC   72
#define DEGC  (NBC * (BSZC / 2))
#define BSZR  16384
#define BSHR  14
#define NBR   13
#define CCR   40
#define PARTC (NBR * BSZR)
#define ZLEN1   (8 * DEGC)
#define ZLEN2   (8 * PARTC)

// ---- big-ws path constants ----
// hcol: u8-packed counts -> 131072 nodes per 128KB LDS bucket -> 2 passes.
// Safe: per-node degree ~Poisson(16); P(deg>200) ~ 1e-90, u8 can't overflow.
#define BSZC3 131072
#define BSHC3 17
#define NBC3  2
#define CCC3  128       // 2*128 = 256 blocks, 1/CU, 128%8==0 (XCD-aligned)
// hrow: float, 32768 nodes / 128KB LDS, 7 passes (proven R9)
#define BSZR2 32768
#define BSHR2 15
#define NBR2  7
#define CCR2  32        // 7*32 = 224 blocks, 1/CU
#define BIGPART (CCR * NBR * BSZR)   // 8519680 words (covers both)

#define NDBLK 782       // ceil(NN/256)
#define XBLOCKS 1024
#define CAPL  4096

#define HB    64        // score-hist partial blocks (NN/HB = 3125 exact)
#define HW    32768     // packed u32 words (2x16-bit counts) = 65536 buckets

// ---- helpers (proven) ----
__device__ __forceinline__ float ldf(const void* p, int i, int bf) {
  if (bf) return __bfloat162float(((const __hip_bfloat16*)p)[i]);
  return ((const float*)p)[i];
}
__device__ __forceinline__ void stf(void* p, int i, float v, int bf) {
  if (bf) ((__hip_bfloat16*)p)[i] = __float2bfloat16(v);
  else ((float*)p)[i] = v;
}
__device__ __forceinline__ float bfu(unsigned u) {   // low 16 bits -> bf16 value
  return __uint_as_float(u << 16);
}
__device__ __forceinline__ float wsum(float v) {
#pragma unroll
  for (int m = 32; m >= 1; m >>= 1) v += __shfl_xor(v, m, 64);
  return v;
}
__device__ __forceinline__ int wsumi(int v) {
#pragma unroll
  for (int m = 32; m >= 1; m >>= 1) v += __shfl_xor(v, m, 64);
  return v;
}
__device__ __forceinline__ unsigned sortkey(float f) {
  unsigned u = __float_as_uint(f);
  return (u & 0x80000000u) ? ~u : (u | 0x80000000u);
}

// ---- dtype detector (proven) ----
__global__ void k_detect(const unsigned short* x16, int* flag) {
  __shared__ int cnt;
  if (threadIdx.x == 0) cnt = 0;
  __syncthreads();
  int ok = 0;
  for (int k = threadIdx.x; k < 512; k += 256) {
    unsigned short u = x16[2 * k];
    int e = (u >> 7) & 0xFF;
    if (u == 0 || (e >= 100 && e <= 150)) ok++;
  }
  atomicAdd(&cnt, ok);
  __syncthreads();
  if (threadIdx.x == 0) flag[0] = (cnt >= 400) ? 1 : 0;
}

// ================= BIG-WS PATH =============================================

// degree histogram, u8-packed: 131072 nodes / 128KB LDS, 2 passes
__global__ void __launch_bounds__(HTH) k_hcolB(const int* __restrict__ col,
                                               unsigned* __restrict__ part) {
  __shared__ unsigned lh[BSZC3 / 4];   // 32768 u32 = 128KB, 4 u8 counters each
  int t = threadIdx.x;
  int b = blockIdx.x / CCC3, j = blockIdx.x % CCC3;
  for (int k = t; k < BSZC3 / 4; k += HTH) lh[k] = 0u;
  __syncthreads();
  int base = b << BSHC3;
  const int4* c4 = (const int4*)col;
  const int stride = CCC3 * HTH;
  for (int i0 = j * HTH + t; i0 < NI4; i0 += 4 * stride) {
    int4 v[4];
#pragma unroll
    for (int u = 0; u < 4; u++) {
      int idx = i0 + u * stride;
      if (idx < NI4) v[u] = c4[idx];
      else { v[u].x = -1; v[u].y = -1; v[u].z = -1; v[u].w = -1; }  // sentinel
    }
#pragma unroll
    for (int u = 0; u < 4; u++) {
      int a0 = v[u].x - base, a1 = v[u].y - base, a2 = v[u].z - base, a3 = v[u].w - base;
      if ((unsigned)a0 < (unsigned)BSZC3) atomicAdd(&lh[a0 >> 2], 1u << ((a0 & 3) * 8));
      if ((unsigned)a1 < (unsigned)BSZC3) atomicAdd(&lh[a1 >> 2], 1u << ((a1 & 3) * 8));
      if ((unsigned)a2 < (unsigned)BSZC3) atomicAdd(&lh[a2 >> 2], 1u << ((a2 & 3) * 8));
      if ((unsigned)a3 < (unsigned)BSZC3) atomicAdd(&lh[a3 >> 2], 1u << ((a3 & 3) * 8));
    }
  }
  __syncthreads();
  unsigned* dst = part + (size_t)blockIdx.x * (BSZC3 / 4);
  for (int k = 4 * t; k < BSZC3 / 4; k += 4 * HTH)
    *(uint4*)&dst[k] = *(const uint4*)&lh[k];
}

__global__ void k_redAB(const unsigned* __restrict__ part, float* __restrict__ dis,
                        const void* docf, const void* dw, const void* db,
                        float* __restrict__ d, const int* flagp) {
  if (blockIdx.x < NDBLK) {
    int i = blockIdx.x * 256 + threadIdx.x;
    if (i < NN) {
      int b = i >> BSHC3;
      int w = i & (BSZC3 - 1);
      int sh = (w & 3) * 8;
      const unsigned* p = part + (size_t)b * CCC3 * (BSZC3 / 4) + (w >> 2);
      int deg = 1;
#pragma unroll 8
      for (int j = 0; j < CCC3; j++)
        deg += (int)((p[(size_t)j * (BSZC3 / 4)] >> sh) & 255u);
      dis[i] = rsqrtf((float)deg);
    }
  } else {
    int flag = flagp[0];
    int o = (blockIdx.x - NDBLK) * 4 + (threadIdx.x >> 6);
    int lane = threadIdx.x & 63;
    float acc = 0.f;
    for (int k = lane; k < DDIMC; k += 64) acc += ldf(docf, k, flag) * ldf(dw, o * DDIMC + k, flag);
    acc = wsum(acc);
    if (lane == 0) d[o] = fmaxf(acc + ldf(db, o, flag), 0.0f);
  }
}

__global__ void __launch_bounds__(HTH) k_hrowB(const int* __restrict__ row, const int* __restrict__ col,
                                               const float* __restrict__ dis,
                                               float* __restrict__ part) {
  __shared__ float lh[BSZR2];          // 128KB
  int t = threadIdx.x;
  int b = blockIdx.x / CCR2, j = blockIdx.x % CCR2;
  for (int k = t; k < BSZR2; k += HTH) lh[k] = 0.f;
  __syncthreads();
  int base = b << BSHR2;
  const int4* r4 = (const int4*)row;
  const int4* c4 = (const int4*)col;
  const int stride = CCR2 * HTH;
  for (int i0 = j * HTH + t; i0 < NI4; i0 += 4 * stride) {
    int4 r[4], c[4];
#pragma unroll
    for (int u = 0; u < 4; u++) {
      int idx = i0 + u * stride;
      if (idx < NI4) { r[u] = r4[idx]; c[u] = c4[idx]; }
      else { r[u].x = -1; r[u].y = -1; r[u].z = -1; r[u].w = -1;    // sentinel
             c[u].x = 0;  c[u].y = 0;  c[u].z = 0;  c[u].w = 0; }
    }
#pragma unroll
    for (int u = 0; u < 4; u++) {
      int a0 = r[u].x - base, a1 = r[u].y - base, a2 = r[u].z - base, a3 = r[u].w - base;
      if ((unsigned)a0 < (unsigned)BSZR2) atomicAdd(&lh[a0], dis[c[u].x]);
      if ((unsigned)a1 < (unsigned)BSZR2) atomicAdd(&lh[a1], dis[c[u].y]);
      if ((unsigned)a2 < (unsigned)BSZR2) atomicAdd(&lh[a2], dis[c[u].z]);
      if ((unsigned)a3 < (unsigned)BSZR2) atomicAdd(&lh[a3], dis[c[u].w]);
    }
  }
  __syncthreads();
  float* dst = part + (size_t)blockIdx.x * BSZR2;
  for (int k = 4 * t; k < BSZR2; k += 4 * HTH)
    *(float4*)&dst[k] = *(const float4*)&lh[k];
}

__global__ void k_redBB(const float* __restrict__ part, const float* __restrict__ dis,
                        float* __restrict__ c) {
  int i = blockIdx.x * 256 + threadIdx.x;
  if (i < NN) {
    int b = i >> BSHR2;
    int k = i & (BSZR2 - 1);
    const float* p = part + (size_t)b * CCR2 * BSZR2 + k;
    float s = 0.f;
#pragma unroll 8
    for (int j = 0; j < CCR2; j++) s += p[(size_t)j * BSZR2];
    float dv = dis[i];
    c[i] = dv * s + dv * dv;
  }
}

// ================= FALLBACK PATH (proven): 64KB LDS, atomic 8-copy merge ====
__global__ void __launch_bounds__(HTH) k_hcol(const int* __restrict__ col,
                                              unsigned* __restrict__ degm) {
  __shared__ unsigned lh[BSZC / 2];
  int t = threadIdx.x;
  int b = blockIdx.x / CCC, j = blockIdx.x % CCC;
  for (int k = t; k < BSZC / 2; k += HTH) lh[k] = 0u;
  __syncthreads();
  int base = b << BSHC;
  const int4* c4 = (const int4*)col;
  const int stride = CCC * HTH;
  for (int i = j * HTH + t; i < NI4; i += 2 * stride) {
    int4 v0 = c4[i];
    int i2 = i + stride;
    int4 v1; v1.x = v1.y = v1.z = v1.w = -1;
    if (i2 < NI4) v1 = c4[i2];
    {
      int a0 = v0.x - base, a1 = v0.y - base, a2 = v0.z - base, a3 = v0.w - base;
      if ((unsigned)a0 < (unsigned)BSZC) atomicAdd(&lh[a0 >> 1], 1u << ((a0 & 1) * 16));
      if ((unsigned)a1 < (unsigned)BSZC) atomicAdd(&lh[a1 >> 1], 1u << ((a1 & 1) * 16));
      if ((unsigned)a2 < (unsigned)BSZC) atomicAdd(&lh[a2 >> 1], 1u << ((a2 & 1) * 16));
      if ((unsigned)a3 < (unsigned)BSZC) atomicAdd(&lh[a3 >> 1], 1u << ((a3 & 1) * 16));
    }
    {
      int a0 = v1.x - base, a1 = v1.y - base, a2 = v1.z - base, a3 = v1.w - base;
      if ((unsigned)a0 < (unsigned)BSZC) atomicAdd(&lh[a0 >> 1], 1u << ((a0 & 1) * 16));
      if ((unsigned)a1 < (unsigned)BSZC) atomicAdd(&lh[a1 >> 1], 1u << ((a1 & 1) * 16));
      if ((unsigned)a2 < (unsigned)BSZC) atomicAdd(&lh[a2 >> 1], 1u << ((a2 & 1) * 16));
      if ((unsigned)a3 < (unsigned)BSZC) atomicAdd(&lh[a3 >> 1], 1u << ((a3 & 1) * 16));
    }
  }
  __syncthreads();
  unsigned* dst = degm + (size_t)(j & 7) * DEGC + (size_t)b * (BSZC / 2);
  for (int k = t; k < BSZC / 2; k += HTH) {
    unsigned v = lh[k];
    if (v) atomicAdd(&dst[k], v);
  }
}

__global__ void k_redA(const unsigned* __restrict__ degm, float* __restrict__ dis,
                       const void* docf, const void* dw, const void* db,
                       float* __restrict__ d, const int* flagp) {
  if (blockIdx.x < NDBLK) {
    int i = blockIdx.x * 256 + threadIdx.x;
    if (i < NN) {
      int sh = (i & 1) * 16;
      int deg = 1;
#pragma unroll
      for (int p = 0; p < 8; p++) {
        unsigned w_ = degm[(size_t)p * DEGC + (i >> 1)];
        deg += (int)((w_ >> sh) & 0xffffu);
      }
      dis[i] = rsqrtf((float)deg);
    }
  } else {
    int flag = flagp[0];
    int o = (blockIdx.x - NDBLK) * 4 + (threadIdx.x >> 6);
    int lane = threadIdx.x & 63;
    float acc = 0.f;
    for (int k = lane; k < DDIMC; k += 64) acc += ldf(docf, k, flag) * ldf(dw, o * DDIMC + k, flag);
    acc = wsum(acc);
    if (lane == 0) d[o] = fmaxf(acc + ldf(db, o, flag), 0.0f);
  }
}

__global__ void __launch_bounds__(HTH) k_hrow(const int* __restrict__ row, const int* __restrict__ col,
                                              const float* __restrict__ dis,
                                              float* __restrict__ partm) {
  __shared__ float lh[BSZR];
  int t = threadIdx.x;
  int b = blockIdx.x / CCR, j = blockIdx.x % CCR;
  for (int k = t; k < BSZR; k += HTH) lh[k] = 0.f;
  __syncthreads();
  int base = b << BSHR;
  const int4* r4 = (const int4*)row;
  const int4* c4 = (const int4*)col;
  const int stride = CCR * HTH;
  for (int i = j * HTH + t; i < NI4; i += 2 * stride) {
    int4 r0 = r4[i];
    int4 c0 = c4[i];
    int i2 = i + stride;
    int4 r1; r1.x = r1.y = r1.z = r1.w = -1;
    int4 c1; c1.x = c1.y = c1.z = c1.w = 0;
    if (i2 < NI4) { r1 = r4[i2]; c1 = c4[i2]; }
    {
      int a0 = r0.x - base, a1 = r0.y - base, a2 = r0.z - base, a3 = r0.w - base;
      if ((unsigned)a0 < (unsigned)BSZR) atomicAdd(&lh[a0], dis[c0.x]);
      if ((unsigned)a1 < (unsigned)BSZR) atomicAdd(&lh[a1], dis[c0.y]);
      if ((unsigned)a2 < (unsigned)BSZR) atomicAdd(&lh[a2], dis[c0.z]);
      if ((unsigned)a3 < (unsigned)BSZR) atomicAdd(&lh[a3], dis[c0.w]);
    }
    {
      int a0 = r1.x - base, a1 = r1.y - base, a2 = r1.z - base, a3 = r1.w - base;
      if ((unsigned)a0 < (unsigned)BSZR) atomicAdd(&lh[a0], dis[c1.x]);
      if ((unsigned)a1 < (unsigned)BSZR) atomicAdd(&lh[a1], dis[c1.y]);
      if ((unsigned)a2 < (unsigned)BSZR) atomicAdd(&lh[a2], dis[c1.z]);
      if ((unsigned)a3 < (unsigned)BSZR) atomicAdd(&lh[a3], dis[c1.w]);
    }
  }
  __syncthreads();
  float* dst = partm + (size_t)(j & 7) * PARTC + (size_t)b * BSZR;
  for (int k = t; k < BSZR; k += HTH) {
    float v = lh[k];
    if (v != 0.f) atomicAdd(&dst[k], v);
  }
}

__global__ void k_redB(const float* __restrict__ partm, const float* __restrict__ dis,
                       float* __restrict__ c) {
  int i = blockIdx.x * 256 + threadIdx.x;
  if (i < NN) {
    float s = 0.f;
#pragma unroll
    for (int p = 0; p < 8; p++) s += partm[(size_t)p * PARTC + i];
    float dv = dis[i];
    c[i] = dv * s + dv * dv;
  }
}

// ---- fused x pass (proven R2): pure stream, score + column accumulator ----
__global__ void k_x(const void* x, const void* pw, const float* __restrict__ c,
                    float* __restrict__ score,
                    float* __restrict__ s8, const int* flagp) {
  __shared__ float sred[4][64];
  int flag = flagp[0];
  int t = threadIdx.x;
  int lane = t & 63;
  int w = t >> 6;
  int wid = (blockIdx.x * 256 + t) >> 6;
  int nw = (gridDim.x * 256) >> 6;

  if (flag) {
    int g  = lane >> 3;
    int c0 = (lane & 7) * 8;
    float pwv[8];
#pragma unroll
    for (int j = 0; j < 8; j++) pwv[j] = ldf(pw, c0 + j, 1);
    float s = 0.f;
#pragma unroll
    for (int j = 0; j < 8; j++) s += pwv[j] * pwv[j];
    float inv = 1.0f / sqrtf(wsum(s) * 0.125f);
    float sacc[8] = {0.f, 0.f, 0.f, 0.f, 0.f, 0.f, 0.f, 0.f};
    const uint4* x4 = (const uint4*)x;
    for (int r0 = wid * 8; r0 < NN; r0 += nw * 8) {
      int r = r0 + g;
      uint4 u = x4[r * 8 + (lane & 7)];
      float xv[8] = { bfu(u.x & 0xffff), bfu(u.x >> 16),
                      bfu(u.y & 0xffff), bfu(u.y >> 16),
                      bfu(u.z & 0xffff), bfu(u.z >> 16),
                      bfu(u.w & 0xffff), bfu(u.w >> 16) };
      float dot = 0.f;
#pragma unroll
      for (int j = 0; j < 8; j++) dot += xv[j] * pwv[j];
      dot += __shfl_xor(dot, 1, 64);
      dot += __shfl_xor(dot, 2, 64);
      dot += __shfl_xor(dot, 4, 64);
      float cr = c[r];
#pragma unroll
      for (int j = 0; j < 8; j++) sacc[j] += cr * xv[j];
      if ((lane & 7) == 0) score[r] = dot * inv;
    }
#pragma unroll
    for (int j = 0; j < 8; j++) {
      sacc[j] += __shfl_xor(sacc[j], 8, 64);
      sacc[j] += __shfl_xor(sacc[j], 16, 64);
      sacc[j] += __shfl_xor(sacc[j], 32, 64);
    }
    if (lane < 8) {
#pragma unroll
      for (int j = 0; j < 8; j++) sred[w][lane * 8 + j] = sacc[j];
    }
  } else {
    int g  = lane >> 4;
    int c0 = (lane & 15) * 4;
    float pwv[4];
#pragma unroll
    for (int j = 0; j < 4; j++) pwv[j] = ((const float*)pw)[c0 + j];
    float s = 0.f;
#pragma unroll
    for (int j = 0; j < 4; j++) s += pwv[j] * pwv[j];
    float inv = 1.0f / sqrtf(wsum(s) * (1.f / 16.f));
    float sacc[4] = {0.f, 0.f, 0.f, 0.f};
    const float4* x4 = (const float4*)x;
    for (int r0 = wid * 4; r0 < NN; r0 += nw * 4) {
      int r = r0 + g;
      float4 v = x4[r * 16 + (lane & 15)];
      float xv[4] = { v.x, v.y, v.z, v.w };
      float dot = 0.f;
#pragma unroll
      for (int j = 0; j < 4; j++) dot += xv[j] * pwv[j];
      dot += __shfl_xor(dot, 1, 64);
      dot += __shfl_xor(dot, 2, 64);
      dot += __shfl_xor(dot, 4, 64);
      dot += __shfl_xor(dot, 8, 64);
      float cr = c[r];
#pragma unroll
      for (int j = 0; j < 4; j++) sacc[j] += cr * xv[j];
      if ((lane & 15) == 0) score[r] = dot * inv;
    }
#pragma unroll
    for (int j = 0; j < 4; j++) {
      sacc[j] += __shfl_xor(sacc[j], 16, 64);
      sacc[j] += __shfl_xor(sacc[j], 32, 64);
    }
    if (lane < 16) {
#pragma unroll
      for (int j = 0; j < 4; j++) sred[w][lane * 4 + j] = sacc[j];
    }
  }
  __syncthreads();
  if (w == 0)
    atomicAdd(&s8[(blockIdx.x & 7) * 64 + lane],
              sred[0][lane] + sred[1][lane] + sred[2][lane] + sred[3][lane]);
}

// ---- LDS-privatized full-resolution score histogram (proven R2) ----
__global__ void __launch_bounds__(1024) k_hist(const float* __restrict__ score,
                                               unsigned* __restrict__ part) {
  __shared__ unsigned lh[HW];
  int t = threadIdx.x;
  for (int k = t; k < HW; k += 1024) lh[k] = 0u;
  __syncthreads();
  int r0 = blockIdx.x * (NN / HB);
  int r1 = r0 + (NN / HB);
  for (int i = r0 + t; i < r1; i += 1024) {
    unsigned b = sortkey(score[i]) >> 16;
    atomicAdd(&lh[b >> 1], 1u << ((b & 1) * 16));
  }
  __syncthreads();
  unsigned* dst = part + (size_t)blockIdx.x * HW;
  for (int k = t; k < HW; k += 1024) dst[k] = lh[k];
}

// ---- sum HB packed partials -> hist (proven R2) ----
__global__ void k_redH(const unsigned* __restrict__ part, int* __restrict__ hist) {
  int w = blockIdx.x * 256 + threadIdx.x;
  unsigned lo = 0, hi = 0;
  for (int b = 0; b < HB; b++) {
    unsigned v = part[(size_t)b * HW + w];
    lo += v & 0xffffu;
    hi += v >> 16;
  }
  hist[2 * w]     = (int)lo;
  hist[2 * w + 1] = (int)hi;
}

// ---- threshold (proven) ----
__global__ void k_thresh(const int* __restrict__ hist, int* __restrict__ thrB,
                         const float* __restrict__ s8, float* __restrict__ svec) {
  __shared__ int part[256];
  __shared__ int segl[256];
  __shared__ int res2[2];
  int t = threadIdx.x, w = t >> 6, lane = t & 63;
  if (t < 64) {
    float a = 0.f;
    for (int r = 0; r < 8; r++) a += s8[r * 64 + t];
    svec[t] = a;
  }
  for (int m = w; m < 256; m += 4) {
    const int* hb = &hist[m * 256];
    int a = hb[lane] + hb[lane + 64] + hb[lane + 128] + hb[lane + 192];
    a = wsumi(a);
    if (lane == 0) part[m] = a;
  }
  __syncthreads();
  if (t == 0) {
    int acc = 0, seg = 0, above = 0;
    for (int b = 255; b >= 0; b--) {
      if (acc + part[b] >= 64) { seg = b; above = acc; break; }
      acc += part[b];
    }
    res2[0] = seg; res2[1] = above;
  }
  __syncthreads();
  segl[t] = hist[res2[0] * 256 + t];
  __syncthreads();
  if (t == 0) {
    int acc = res2[1], B = res2[0] * 256;
    for (int j = 255; j >= 0; j--) {
      acc += segl[j];
      if (acc >= 64) { B = res2[0] * 256 + j; break; }
    }
    thrB[0] = B;
  }
}

// ---- collect (proven) ----
__global__ void k_collect(const float* __restrict__ score, const int* __restrict__ thrB,
                          int* __restrict__ candn, unsigned* __restrict__ ckey,
                          int* __restrict__ cidx) {
  int i = blockIdx.x * blockDim.x + threadIdx.x;
  if (i >= NN) return;
  unsigned u = sortkey(score[i]);
  if ((int)(u >> 16) >= thrB[0]) {
    int p = atomicAdd(candn, 1);
    if (p < CAPL) { ckey[p] = u; cidx[p] = i; }
  }
}

// ---- top-64 (1024 threads, proven) ----
__global__ void __launch_bounds__(1024) k_top(const int* __restrict__ candn,
                      const unsigned* __restrict__ ckey,
                      const int* __restrict__ cidx, const void* x,
                      float* __restrict__ xt, const int* flagp) {
  __shared__ unsigned long long keys[CAPL];
  __shared__ int perm[64];
  __shared__ float ts[64];
  int flag = flagp[0];
  int t = threadIdx.x;
  int M = candn[0];
  if (M > CAPL) M = CAPL;
  for (int j = t; j < M; j += 1024)
    keys[j] = (((unsigned long long)ckey[j]) << 32) |
              (unsigned long long)(0xFFFFFFFFu - (unsigned)cidx[j]);
  __syncthreads();
  for (int j = t; j < M; j += 1024) {
    unsigned long long k = keys[j];
    int rank = 0;
    for (int i = 0; i < M; i++) rank += (keys[i] > k) ? 1 : 0;
    if (rank < 64) {
      unsigned ku = (unsigned)(k >> 32);
      unsigned idx = 0xFFFFFFFFu - (unsigned)(k & 0xFFFFFFFFu);
      perm[rank] = (int)idx;
      unsigned bits = (ku & 0x80000000u) ? (ku ^ 0x80000000u) : ~ku;
      ts[rank] = tanhf(__uint_as_float(bits));
    }
  }
  __syncthreads();
  for (int q = t; q < 4096; q += 1024) {
    int j = q >> 6, f = q & 63;
    xt[q] = ldf(x, perm[j] * 64 + f, flag) * ts[j];
  }
}

// ---- GRU (proven round-0 rework): coalesced staging, LDS-side transpose ----
#define GS 193
__device__ __forceinline__ void stage_w(const void* src, float* dst, int flag, int t) {
  if (flag) {
    const uint4* s4 = (const uint4*)src;
    for (int k = t; k < 1536; k += 256) {
      uint4 u = s4[k];
      int e = k << 3; int o = e >> 6, f = e & 63;
      float* d_ = &dst[f * GS + o];
      d_[0]      = bfu(u.x & 0xffff); d_[GS]     = bfu(u.x >> 16);
      d_[2 * GS] = bfu(u.y & 0xffff); d_[3 * GS] = bfu(u.y >> 16);
      d_[4 * GS] = bfu(u.z & 0xffff); d_[5 * GS] = bfu(u.z >> 16);
      d_[6 * GS] = bfu(u.w & 0xffff); d_[7 * GS] = bfu(u.w >> 16);
    }
  } else {
    const float4* s4 = (const float4*)src;
    for (int k = t; k < 3072; k += 256) {
      float4 v = s4[k];
      int e = k << 2; int o = e >> 6, f = e & 63;
      float* d_ = &dst[f * GS + o];
      d_[0] = v.x; d_[GS] = v.y; d_[2 * GS] = v.z; d_[3 * GS] = v.w;
    }
  }
}

__global__ void k_gru(const float* __restrict__ xt, const void* h0g, const void* wihg,
                      const void* whhg, const void* bihg, const void* bhhg,
                      float* __restrict__ Wout, const int* flagp) {
  __shared__ float wb1[64 * GS];
  __shared__ float wb2[64 * GS];
  __shared__ float xtr[256];
  __shared__ float h0r[256];
  int flag = flagp[0];
  int t = threadIdx.x;
  int j0 = blockIdx.x * 4;
  { int jj = t >> 6, f = t & 63;
    xtr[t] = xt[(j0 + jj) * 64 + f];
    h0r[t] = ldf(h0g, (j0 + jj) * 64 + f, flag); }
  stage_w(wihg, wb1, flag, t);
  stage_w(whhg, wb2, flag, t);
  __syncthreads();
  int jl = t >> 6, c2 = t & 63;
  float xr = 0, xz = 0, xn = 0, hr = 0, hz = 0, hn = 0;
#pragma unroll 4
  for (int f = 0; f < 64; f++) {
    float xv = xtr[jl * 64 + f];
    float hv = h0r[jl * 64 + f];
    const float* w1 = &wb1[f * GS];
    const float* w2 = &wb2[f * GS];
    xr += xv * w1[c2]; xz += xv * w1[64 + c2]; xn += xv * w1[128 + c2];
    hr += hv * w2[c2]; hz += hv * w2[64 + c2]; hn += hv * w2[128 + c2];
  }
  xr += ldf(bihg, c2, flag); xz += ldf(bihg, 64 + c2, flag); xn += ldf(bihg, 128 + c2, flag);
  hr += ldf(bhhg, c2, flag); hz += ldf(bhhg, 64 + c2, flag); hn += ldf(bhhg, 128 + c2, flag);
  float rg = 1.f / (1.f + expf(-(xr + hr)));
  float zg = 1.f / (1.f + expf(-(xz + hz)));
  float nc = tanhf(xn + rg * hn);
  Wout[(j0 + jl) * 64 + c2] = (1.f - zg) * nc + zg * h0r[jl * 64 + c2];
}

// ---- tail stage 1 (R9 proven, restored): 64 blocks spread weight reads ----
__global__ void k_g(const float* __restrict__ svec, const float* __restrict__ Wm,
                    const void* gw, const void* gb, float* __restrict__ g,
                    const int* flagp) {
  __shared__ float pooled[64];
  int flag = flagp[0];
  int t = threadIdx.x, w = t >> 6, lane = t & 63;
  if (t < 64) {
    float a = 0.f;
    for (int f = 0; f < 64; f++) a += svec[f] * Wm[f * 64 + t];
    pooled[t] = a * (1.0f / (float)NN);
  }
  __syncthreads();
  int o = blockIdx.x * 4 + w;
  float acc = pooled[lane] * ldf(gw, o * 64 + lane, flag);
  acc = wsum(acc);
  if (lane == 0) g[o] = acc + ldf(gb, o, flag);
}

// ---- tail stage 2 (R9 proven, restored) ----
__global__ void k_ln(const float* __restrict__ g, const float* __restrict__ d,
                     const void* lng, const void* lnb, float* __restrict__ lnv,
                     const int* flagp) {
  __shared__ float red[256];
  __shared__ float stats[2];
  int flag = flagp[0];
  int t = threadIdx.x;
  float v0 = g[t], v1 = d[t];
  red[t] = v0 + v1; __syncthreads();
  for (int s = 128; s > 0; s >>= 1) { if (t < s) red[t] += red[t + s]; __syncthreads(); }
  if (t == 0) stats[0] = red[0];
  __syncthreads();
  red[t] = v0 * v0 + v1 * v1; __syncthreads();
  for (int s = 128; s > 0; s >>= 1) { if (t < s) red[t] += red[t + s]; __syncthreads(); }
  if (t == 0) stats[1] = red[0];
  __syncthreads();
  float mu = stats[0] * (1.f / 512.f);
  float var = stats[1] * (1.f / 512.f) - mu * mu;
  float istd = rsqrtf(var + 1e-5f);
  lnv[t]       = (v0 - mu) * istd * ldf(lng, t, flag)       + ldf(lnb, t, flag);
  lnv[t + 256] = (v1 - mu) * istd * ldf(lng, t + 256, flag) + ldf(lnb, t + 256, flag);
}

// ---- tail stage 3 (R9 proven, restored) ----
__global__ void k_fuse(const float* __restrict__ lnv, const void* fw, const void* fb,
                       float* __restrict__ h1, const int* flagp) {
  __shared__ float lv[512];
  int flag = flagp[0];
  int t = threadIdx.x, w = t >> 6, lane = t & 63;
  lv[t] = lnv[t]; lv[t + 256] = lnv[t + 256];
  __syncthreads();
  int o = blockIdx.x * 4 + w;
  float acc = 0.f;
  if (flag) {
    uint4 u = *((const uint4*)((const unsigned short*)fw + o * 512) + lane);
    const float* l = &lv[lane * 8];
    acc = bfu(u.x & 0xffff) * l[0] + bfu(u.x >> 16) * l[1]
        + bfu(u.y & 0xffff) * l[2] + bfu(u.y >> 16) * l[3]
        + bfu(u.z & 0xffff) * l[4] + bfu(u.z >> 16) * l[5]
        + bfu(u.w & 0xffff) * l[6] + bfu(u.w >> 16) * l[7];
  } else {
    const float4* fv = (const float4*)((const float*)fw + o * 512);
    float4 a = fv[lane * 2], b = fv[lane * 2 + 1];
    const float* l = &lv[lane * 8];
    acc = a.x * l[0] + a.y * l[1] + a.z * l[2] + a.w * l[3]
        + b.x * l[4] + b.y * l[5] + b.z * l[6] + b.w * l[7];
  }
  acc = wsum(acc);
  if (lane == 0) h1[o] = fmaxf(acc + ldf(fb, o, flag), 0.0f);
}

// ---- tail stage 4 (R9 proven, restored) ----
__global__ void k_out(const float* __restrict__ h1, const void* tw, const void* tb,
                      const void* tmw, const void* tmb, void* out, const int* flagp) {
  int flag = flagp[0];
  int t = threadIdx.x, w = t >> 6, lane = t & 63;
  int o = blockIdx.x * 4 + w;
  if (o >= 17) return;
  float acc = 0.f;
  if (o < 16) { for (int k = lane; k < 256; k += 64) acc += h1[k] * ldf(tw, o * 256 + k, flag); }
  else        { for (int k = lane; k < 256; k += 64) acc += h1[k] * ldf(tmw, k, flag); }
  acc = wsum(acc);
  if (lane == 0) {
    float bias = (o < 16) ? ldf(tb, o, flag) : ldf(tmb, 0, flag);
    stf(out, o, acc + bias, flag);
  }
}

extern "C" void kernel_launch(void* const* d_in, const int* in_sizes, int n_in,
                              void* d_out, int out_size, void* d_ws, size_t ws_size,
                              hipStream_t stream) {
  const void* x    = d_in[0];
  const int*  ei   = (const int*)d_in[1];
  const void* docf = d_in[2];
  const void* pw   = d_in[3];
  const void* h0   = d_in[4];
  const void* wih  = d_in[5];
  const void* whh  = d_in[6];
  const void* bih  = d_in[7];
  const void* bhh  = d_in[8];
  const void* gw   = d_in[9];
  const void* gb   = d_in[10];
  const void* dw   = d_in[11];
  const void* db   = d_in[12];
  const void* lng  = d_in[13];
  const void* lnb  = d_in[14];
  const void* fw   = d_in[15];
  const void* fb   = d_in[16];
  const void* tw   = d_in[17];
  const void* tb   = d_in[18];
  const void* tmw  = d_in[19];
  const void* tmb  = d_in[20];

  const int* row = ei;
  const int* col = ei + EE;

  float* wsf = (float*)d_ws;
  int*   wsi = (int*)d_ws;

  int big = (ws_size >= (size_t)42 * 1024 * 1024);
  size_t base = big ? (size_t)BIGPART : (size_t)PARTW;

  size_t oHIST  = base;
  size_t oCANDN = oHIST + 65536;
  size_t oS8    = oCANDN + 8;
  size_t oFLAG  = oS8 + 512;
  size_t oTHR   = oFLAG + 8;
  size_t oSV    = oTHR + 8;
  size_t oD     = oSV + 64;
  size_t oDIS   = oD + 256;
  size_t oC     = oDIS + NN;
  size_t oSCORE = oC + NN;
  size_t oCKEY  = oSCORE + NN;
  size_t oCIDX  = oCKEY + 4096;
  size_t oXT    = oCIDX + 4096;
  size_t oWW    = oXT + 4096;
  size_t oG     = oWW + 4096;
  size_t oLNV   = oG + 256;
  size_t oH1    = oLNV + 512;

  hipMemsetAsync(wsi + oCANDN, 0, (size_t)(8 + 512) * 4, stream);
  k_detect<<<1, 256, 0, stream>>>((const unsigned short*)x, wsi + oFLAG);

  if (big) {
    k_hcolB<<<NBC3 * CCC3, HTH, 0, stream>>>(col, (unsigned*)wsi);
    k_redAB<<<NDBLK + 64, 256, 0, stream>>>((const unsigned*)wsi, wsf + oDIS,
                                            docf, dw, db, wsf + oD, wsi + oFLAG);
    k_hrowB<<<NBR2 * CCR2, HTH, 0, stream>>>(row, col, wsf + oDIS, wsf);
    k_redBB<<<NDBLK, 256, 0, stream>>>(wsf, wsf + oDIS, wsf + oC);
  } else {
    hipMemsetAsync(wsi, 0, (size_t)ZLEN1 * 4, stream);
    k_hcol<<<NBC * CCC, HTH, 0, stream>>>(col, (unsigned*)wsi);
    k_redA<<<NDBLK + 64, 256, 0, stream>>>((const unsigned*)wsi, wsf + oDIS,
                                           docf, dw, db, wsf + oD, wsi + oFLAG);
    hipMemsetAsync(wsi, 0, (size_t)ZLEN2 * 4, stream);
    k_hrow<<<NBR * CCR, HTH, 0, stream>>>(row, col, wsf + oDIS, wsf);
    k_redB<<<NDBLK, 256, 0, stream>>>(wsf, wsf + oDIS, wsf + oC);
  }

  k_x<<<XBLOCKS, 256, 0, stream>>>(x, pw, wsf + oC, wsf + oSCORE,
                                   wsf + oS8, wsi + oFLAG);
  k_hist<<<HB, 1024, 0, stream>>>(wsf + oSCORE, (unsigned*)wsi);
  k_redH<<<HW / 256, 256, 0, stream>>>((const unsigned*)wsi, wsi + oHIST);
  k_thresh<<<1, 256, 0, stream>>>(wsi + oHIST, wsi + oTHR, wsf + oS8, wsf + oSV);
  k_collect<<<NDBLK, 256, 0, stream>>>(wsf + oSCORE, wsi + oTHR, wsi + oCANDN,
                                       (unsigned*)(wsi + oCKEY), wsi + oCIDX);
  k_top<<<1, 1024, 0, stream>>>(wsi + oCANDN, (const unsigned*)(wsi + oCKEY),
                                wsi + oCIDX, x, wsf + oXT, wsi + oFLAG);
  k_gru<<<16, 256, 0, stream>>>(wsf + oXT, h0, wih, whh, bih, bhh, wsf + oWW, wsi + oFLAG);
  k_g<<<64, 256, 0, stream>>>(wsf + oSV, wsf + oWW, gw, gb, wsf + oG, wsi + oFLAG);
  k_ln<<<1, 256, 0, stream>>>(wsf + oG, wsf + oD, lng, lnb, wsf + oLNV, wsi + oFLAG);
  k_fuse<<<64, 256, 0, stream>>>(wsf + oLNV, fw, fb, wsf + oH1, wsi + oFLAG);
  k_out<<<5, 256, 0, stream>>>(wsf + oH1, tw, tb, tmw, tmb, d_out, wsi + oFLAG);
}

// Round 12
// 281.564 us; speedup vs baseline: 1.1399x; 1.0561x over previous
//
#include <hip/hip_runtime.h>
#include <hip/hip_bf16.h>

#define NN    200000
#define EE    3200000
#define DDIMC 768

#define NI4   800000    // EE/4 int4s
#define HTH   1024      // histogram block threads
#define PARTW (25 * 12 * 8192)   // legacy region size (fallback layout)

// ---- fallback (small-ws) path constants: 64KB LDS, atomic 8-copy merge ----
#define BSZC  32768
#define BSHC  15
#define NBC   7
#define CCC   72
#define DEGC  (NBC * (BSZC / 2))
#define BSZR  16384
#define BSHR  14
#define NBR   13
#define CCR   40
#define PARTC (NBR * BSZR)
#define ZLEN1   (8 * DEGC)
#define ZLEN2   (8 * PARTC)

// ---- big-ws path constants ----
// hcol: u8-packed counts -> 131072 nodes per 128KB LDS bucket -> 2 passes.
// Safe: per-node degree ~Poisson(16); P(deg>200) ~ 1e-90, u8 can't overflow.
#define BSZC3 131072
#define BSHC3 17
#define NBC3  2
#define CCC3  128       // 2*128 = 256 blocks, 1/CU, 128%8==0 (XCD-aligned)
// hrow: float, 32768 nodes / 128KB LDS, 7 passes (proven R9)
#define BSZR2 32768
#define BSHR2 15
#define NBR2  7
#define CCR2  32        // 7*32 = 224 blocks, 1/CU
#define BIGPART (CCR * NBR * BSZR)   // 8519680 words (covers both)

#define NDBLK 782       // ceil(NN/256)
#define XBLOCKS 1024
#define CAPL  4096

#define HB    64        // score-hist partial blocks (NN/HB = 3125 exact)
#define HW    32768     // packed u32 words (2x16-bit counts) = 65536 buckets

// ---- helpers (proven) ----
__device__ __forceinline__ float ldf(const void* p, int i, int bf) {
  if (bf) return __bfloat162float(((const __hip_bfloat16*)p)[i]);
  return ((const float*)p)[i];
}
__device__ __forceinline__ void stf(void* p, int i, float v, int bf) {
  if (bf) ((__hip_bfloat16*)p)[i] = __float2bfloat16(v);
  else ((float*)p)[i] = v;
}
__device__ __forceinline__ float bfu(unsigned u) {   // low 16 bits -> bf16 value
  return __uint_as_float(u << 16);
}
__device__ __forceinline__ float wsum(float v) {
#pragma unroll
  for (int m = 32; m >= 1; m >>= 1) v += __shfl_xor(v, m, 64);
  return v;
}
__device__ __forceinline__ int wsumi(int v) {
#pragma unroll
  for (int m = 32; m >= 1; m >>= 1) v += __shfl_xor(v, m, 64);
  return v;
}
__device__ __forceinline__ unsigned sortkey(float f) {
  unsigned u = __float_as_uint(f);
  return (u & 0x80000000u) ? ~u : (u | 0x80000000u);
}

// ---- dtype detector (proven) ----
__global__ void k_detect(const unsigned short* x16, int* flag) {
  __shared__ int cnt;
  if (threadIdx.x == 0) cnt = 0;
  __syncthreads();
  int ok = 0;
  for (int k = threadIdx.x; k < 512; k += 256) {
    unsigned short u = x16[2 * k];
    int e = (u >> 7) & 0xFF;
    if (u == 0 || (e >= 100 && e <= 150)) ok++;
  }
  atomicAdd(&cnt, ok);
  __syncthreads();
  if (threadIdx.x == 0) flag[0] = (cnt >= 400) ? 1 : 0;
}

// ================= BIG-WS PATH =============================================

// degree histogram, u8-packed: 131072 nodes / 128KB LDS, 2 passes
__global__ void __launch_bounds__(HTH) k_hcolB(const int* __restrict__ col,
                                               unsigned* __restrict__ part) {
  __shared__ unsigned lh[BSZC3 / 4];   // 32768 u32 = 128KB, 4 u8 counters each
  int t = threadIdx.x;
  int b = blockIdx.x / CCC3, j = blockIdx.x % CCC3;
  for (int k = t; k < BSZC3 / 4; k += HTH) lh[k] = 0u;
  __syncthreads();
  int base = b << BSHC3;
  const int4* c4 = (const int4*)col;
  const int stride = CCC3 * HTH;
  for (int i0 = j * HTH + t; i0 < NI4; i0 += 4 * stride) {
    int4 v[4];
#pragma unroll
    for (int u = 0; u < 4; u++) {
      int idx = i0 + u * stride;
      if (idx < NI4) v[u] = c4[idx];
      else { v[u].x = -1; v[u].y = -1; v[u].z = -1; v[u].w = -1; }  // sentinel
    }
#pragma unroll
    for (int u = 0; u < 4; u++) {
      int a0 = v[u].x - base, a1 = v[u].y - base, a2 = v[u].z - base, a3 = v[u].w - base;
      if ((unsigned)a0 < (unsigned)BSZC3) atomicAdd(&lh[a0 >> 2], 1u << ((a0 & 3) * 8));
      if ((unsigned)a1 < (unsigned)BSZC3) atomicAdd(&lh[a1 >> 2], 1u << ((a1 & 3) * 8));
      if ((unsigned)a2 < (unsigned)BSZC3) atomicAdd(&lh[a2 >> 2], 1u << ((a2 & 3) * 8));
      if ((unsigned)a3 < (unsigned)BSZC3) atomicAdd(&lh[a3 >> 2], 1u << ((a3 & 3) * 8));
    }
  }
  __syncthreads();
  unsigned* dst = part + (size_t)blockIdx.x * (BSZC3 / 4);
  for (int k = 4 * t; k < BSZC3 / 4; k += 4 * HTH)
    *(uint4*)&dst[k] = *(const uint4*)&lh[k];
}

__global__ void k_redAB(const unsigned* __restrict__ part, float* __restrict__ dis,
                        const void* docf, const void* dw, const void* db,
                        float* __restrict__ d, const int* flagp) {
  if (blockIdx.x < NDBLK) {
    int i = blockIdx.x * 256 + threadIdx.x;
    if (i < NN) {
      int b = i >> BSHC3;
      int w = i & (BSZC3 - 1);
      int sh = (w & 3) * 8;
      const unsigned* p = part + (size_t)b * CCC3 * (BSZC3 / 4) + (w >> 2);
      int deg = 1;
#pragma unroll 8
      for (int j = 0; j < CCC3; j++)
        deg += (int)((p[(size_t)j * (BSZC3 / 4)] >> sh) & 255u);
      dis[i] = rsqrtf((float)deg);
    }
  } else {
    int flag = flagp[0];
    int o = (blockIdx.x - NDBLK) * 4 + (threadIdx.x >> 6);
    int lane = threadIdx.x & 63;
    float acc = 0.f;
    for (int k = lane; k < DDIMC; k += 64) acc += ldf(docf, k, flag) * ldf(dw, o * DDIMC + k, flag);
    acc = wsum(acc);
    if (lane == 0) d[o] = fmaxf(acc + ldf(db, o, flag), 0.0f);
  }
}

// weighted row histogram (R12 rework): phase-split inner loop.
// Old: load->branch->gather->atomic chained per edge (16 waves/CU can't hide
// ~500cy chains -> 42us). New: batch the 16 predicated dis-gathers into
// statically-indexed regs (all loads in flight), THEN do the 16 LDS atomics.
__global__ void __launch_bounds__(HTH) k_hrowB(const int* __restrict__ row, const int* __restrict__ col,
                                               const float* __restrict__ dis,
                                               float* __restrict__ part) {
  __shared__ float lh[BSZR2];          // 128KB
  int t = threadIdx.x;
  int b = blockIdx.x / CCR2, j = blockIdx.x % CCR2;
  for (int k = t; k < BSZR2; k += HTH) lh[k] = 0.f;
  __syncthreads();
  int base = b << BSHR2;
  const int4* r4 = (const int4*)row;
  const int4* c4 = (const int4*)col;
  const int stride = CCR2 * HTH;
  for (int i0 = j * HTH + t; i0 < NI4; i0 += 4 * stride) {
    int4 r[4], c[4];
#pragma unroll
    for (int u = 0; u < 4; u++) {
      int idx = i0 + u * stride;
      if (idx < NI4) { r[u] = r4[idx]; c[u] = c4[idx]; }
      else { r[u].x = -1; r[u].y = -1; r[u].z = -1; r[u].w = -1;    // sentinel
             c[u].x = 0;  c[u].y = 0;  c[u].z = 0;  c[u].w = 0; }
    }
    int   a[16];
    float wv[16];
#pragma unroll
    for (int u = 0; u < 4; u++) {
      a[4 * u + 0] = r[u].x - base;
      a[4 * u + 1] = r[u].y - base;
      a[4 * u + 2] = r[u].z - base;
      a[4 * u + 3] = r[u].w - base;
    }
    // batch of independent predicated gathers -- all issue before any atomic
#pragma unroll
    for (int u = 0; u < 4; u++) {
      wv[4 * u + 0] = ((unsigned)a[4 * u + 0] < (unsigned)BSZR2) ? dis[c[u].x] : 0.f;
      wv[4 * u + 1] = ((unsigned)a[4 * u + 1] < (unsigned)BSZR2) ? dis[c[u].y] : 0.f;
      wv[4 * u + 2] = ((unsigned)a[4 * u + 2] < (unsigned)BSZR2) ? dis[c[u].z] : 0.f;
      wv[4 * u + 3] = ((unsigned)a[4 * u + 3] < (unsigned)BSZR2) ? dis[c[u].w] : 0.f;
    }
#pragma unroll
    for (int k = 0; k < 16; k++)
      if ((unsigned)a[k] < (unsigned)BSZR2) atomicAdd(&lh[a[k]], wv[k]);
  }
  __syncthreads();
  float* dst = part + (size_t)blockIdx.x * BSZR2;
  for (int k = 4 * t; k < BSZR2; k += 4 * HTH)
    *(float4*)&dst[k] = *(const float4*)&lh[k];
}

__global__ void k_redBB(const float* __restrict__ part, const float* __restrict__ dis,
                        float* __restrict__ c) {
  int i = blockIdx.x * 256 + threadIdx.x;
  if (i < NN) {
    int b = i >> BSHR2;
    int k = i & (BSZR2 - 1);
    const float* p = part + (size_t)b * CCR2 * BSZR2 + k;
    float s = 0.f;
#pragma unroll 8
    for (int j = 0; j < CCR2; j++) s += p[(size_t)j * BSZR2];
    float dv = dis[i];
    c[i] = dv * s + dv * dv;
  }
}

// ================= FALLBACK PATH (proven): 64KB LDS, atomic 8-copy merge ====
__global__ void __launch_bounds__(HTH) k_hcol(const int* __restrict__ col,
                                              unsigned* __restrict__ degm) {
  __shared__ unsigned lh[BSZC / 2];
  int t = threadIdx.x;
  int b = blockIdx.x / CCC, j = blockIdx.x % CCC;
  for (int k = t; k < BSZC / 2; k += HTH) lh[k] = 0u;
  __syncthreads();
  int base = b << BSHC;
  const int4* c4 = (const int4*)col;
  const int stride = CCC * HTH;
  for (int i = j * HTH + t; i < NI4; i += 2 * stride) {
    int4 v0 = c4[i];
    int i2 = i + stride;
    int4 v1; v1.x = v1.y = v1.z = v1.w = -1;
    if (i2 < NI4) v1 = c4[i2];
    {
      int a0 = v0.x - base, a1 = v0.y - base, a2 = v0.z - base, a3 = v0.w - base;
      if ((unsigned)a0 < (unsigned)BSZC) atomicAdd(&lh[a0 >> 1], 1u << ((a0 & 1) * 16));
      if ((unsigned)a1 < (unsigned)BSZC) atomicAdd(&lh[a1 >> 1], 1u << ((a1 & 1) * 16));
      if ((unsigned)a2 < (unsigned)BSZC) atomicAdd(&lh[a2 >> 1], 1u << ((a2 & 1) * 16));
      if ((unsigned)a3 < (unsigned)BSZC) atomicAdd(&lh[a3 >> 1], 1u << ((a3 & 1) * 16));
    }
    {
      int a0 = v1.x - base, a1 = v1.y - base, a2 = v1.z - base, a3 = v1.w - base;
      if ((unsigned)a0 < (unsigned)BSZC) atomicAdd(&lh[a0 >> 1], 1u << ((a0 & 1) * 16));
      if ((unsigned)a1 < (unsigned)BSZC) atomicAdd(&lh[a1 >> 1], 1u << ((a1 & 1) * 16));
      if ((unsigned)a2 < (unsigned)BSZC) atomicAdd(&lh[a2 >> 1], 1u << ((a2 & 1) * 16));
      if ((unsigned)a3 < (unsigned)BSZC) atomicAdd(&lh[a3 >> 1], 1u << ((a3 & 1) * 16));
    }
  }
  __syncthreads();
  unsigned* dst = degm + (size_t)(j & 7) * DEGC + (size_t)b * (BSZC / 2);
  for (int k = t; k < BSZC / 2; k += HTH) {
    unsigned v = lh[k];
    if (v) atomicAdd(&dst[k], v);
  }
}

__global__ void k_redA(const unsigned* __restrict__ degm, float* __restrict__ dis,
                       const void* docf, const void* dw, const void* db,
                       float* __restrict__ d, const int* flagp) {
  if (blockIdx.x < NDBLK) {
    int i = blockIdx.x * 256 + threadIdx.x;
    if (i < NN) {
      int sh = (i & 1) * 16;
      int deg = 1;
#pragma unroll
      for (int p = 0; p < 8; p++) {
        unsigned w_ = degm[(size_t)p * DEGC + (i >> 1)];
        deg += (int)((w_ >> sh) & 0xffffu);
      }
      dis[i] = rsqrtf((float)deg);
    }
  } else {
    int flag = flagp[0];
    int o = (blockIdx.x - NDBLK) * 4 + (threadIdx.x >> 6);
    int lane = threadIdx.x & 63;
    float acc = 0.f;
    for (int k = lane; k < DDIMC; k += 64) acc += ldf(docf, k, flag) * ldf(dw, o * DDIMC + k, flag);
    acc = wsum(acc);
    if (lane == 0) d[o] = fmaxf(acc + ldf(db, o, flag), 0.0f);
  }
}

__global__ void __launch_bounds__(HTH) k_hrow(const int* __restrict__ row, const int* __restrict__ col,
                                              const float* __restrict__ dis,
                                              float* __restrict__ partm) {
  __shared__ float lh[BSZR];
  int t = threadIdx.x;
  int b = blockIdx.x / CCR, j = blockIdx.x % CCR;
  for (int k = t; k < BSZR; k += HTH) lh[k] = 0.f;
  __syncthreads();
  int base = b << BSHR;
  const int4* r4 = (const int4*)row;
  const int4* c4 = (const int4*)col;
  const int stride = CCR * HTH;
  for (int i = j * HTH + t; i < NI4; i += 2 * stride) {
    int4 r0 = r4[i];
    int4 c0 = c4[i];
    int i2 = i + stride;
    int4 r1; r1.x = r1.y = r1.z = r1.w = -1;
    int4 c1; c1.x = c1.y = c1.z = c1.w = 0;
    if (i2 < NI4) { r1 = r4[i2]; c1 = c4[i2]; }
    {
      int a0 = r0.x - base, a1 = r0.y - base, a2 = r0.z - base, a3 = r0.w - base;
      if ((unsigned)a0 < (unsigned)BSZR) atomicAdd(&lh[a0], dis[c0.x]);
      if ((unsigned)a1 < (unsigned)BSZR) atomicAdd(&lh[a1], dis[c0.y]);
      if ((unsigned)a2 < (unsigned)BSZR) atomicAdd(&lh[a2], dis[c0.z]);
      if ((unsigned)a3 < (unsigned)BSZR) atomicAdd(&lh[a3], dis[c0.w]);
    }
    {
      int a0 = r1.x - base, a1 = r1.y - base, a2 = r1.z - base, a3 = r1.w - base;
      if ((unsigned)a0 < (unsigned)BSZR) atomicAdd(&lh[a0], dis[c1.x]);
      if ((unsigned)a1 < (unsigned)BSZR) atomicAdd(&lh[a1], dis[c1.y]);
      if ((unsigned)a2 < (unsigned)BSZR) atomicAdd(&lh[a2], dis[c1.z]);
      if ((unsigned)a3 < (unsigned)BSZR) atomicAdd(&lh[a3], dis[c1.w]);
    }
  }
  __syncthreads();
  float* dst = partm + (size_t)(j & 7) * PARTC + (size_t)b * BSZR;
  for (int k = t; k < BSZR; k += HTH) {
    float v = lh[k];
    if (v != 0.f) atomicAdd(&dst[k], v);
  }
}

__global__ void k_redB(const float* __restrict__ partm, const float* __restrict__ dis,
                       float* __restrict__ c) {
  int i = blockIdx.x * 256 + threadIdx.x;
  if (i < NN) {
    float s = 0.f;
#pragma unroll
    for (int p = 0; p < 8; p++) s += partm[(size_t)p * PARTC + i];
    float dv = dis[i];
    c[i] = dv * s + dv * dv;
  }
}

// ---- fused x pass (proven R2): pure stream, score + column accumulator ----
__global__ void k_x(const void* x, const void* pw, const float* __restrict__ c,
                    float* __restrict__ score,
                    float* __restrict__ s8, const int* flagp) {
  __shared__ float sred[4][64];
  int flag = flagp[0];
  int t = threadIdx.x;
  int lane = t & 63;
  int w = t >> 6;
  int wid = (blockIdx.x * 256 + t) >> 6;
  int nw = (gridDim.x * 256) >> 6;

  if (flag) {
    int g  = lane >> 3;
    int c0 = (lane & 7) * 8;
    float pwv[8];
#pragma unroll
    for (int j = 0; j < 8; j++) pwv[j] = ldf(pw, c0 + j, 1);
    float s = 0.f;
#pragma unroll
    for (int j = 0; j < 8; j++) s += pwv[j] * pwv[j];
    float inv = 1.0f / sqrtf(wsum(s) * 0.125f);
    float sacc[8] = {0.f, 0.f, 0.f, 0.f, 0.f, 0.f, 0.f, 0.f};
    const uint4* x4 = (const uint4*)x;
    for (int r0 = wid * 8; r0 < NN; r0 += nw * 8) {
      int r = r0 + g;
      uint4 u = x4[r * 8 + (lane & 7)];
      float xv[8] = { bfu(u.x & 0xffff), bfu(u.x >> 16),
                      bfu(u.y & 0xffff), bfu(u.y >> 16),
                      bfu(u.z & 0xffff), bfu(u.z >> 16),
                      bfu(u.w & 0xffff), bfu(u.w >> 16) };
      float dot = 0.f;
#pragma unroll
      for (int j = 0; j < 8; j++) dot += xv[j] * pwv[j];
      dot += __shfl_xor(dot, 1, 64);
      dot += __shfl_xor(dot, 2, 64);
      dot += __shfl_xor(dot, 4, 64);
      float cr = c[r];
#pragma unroll
      for (int j = 0; j < 8; j++) sacc[j] += cr * xv[j];
      if ((lane & 7) == 0) score[r] = dot * inv;
    }
#pragma unroll
    for (int j = 0; j < 8; j++) {
      sacc[j] += __shfl_xor(sacc[j], 8, 64);
      sacc[j] += __shfl_xor(sacc[j], 16, 64);
      sacc[j] += __shfl_xor(sacc[j], 32, 64);
    }
    if (lane < 8) {
#pragma unroll
      for (int j = 0; j < 8; j++) sred[w][lane * 8 + j] = sacc[j];
    }
  } else {
    int g  = lane >> 4;
    int c0 = (lane & 15) * 4;
    float pwv[4];
#pragma unroll
    for (int j = 0; j < 4; j++) pwv[j] = ((const float*)pw)[c0 + j];
    float s = 0.f;
#pragma unroll
    for (int j = 0; j < 4; j++) s += pwv[j] * pwv[j];
    float inv = 1.0f / sqrtf(wsum(s) * (1.f / 16.f));
    float sacc[4] = {0.f, 0.f, 0.f, 0.f};
    const float4* x4 = (const float4*)x;
    for (int r0 = wid * 4; r0 < NN; r0 += nw * 4) {
      int r = r0 + g;
      float4 v = x4[r * 16 + (lane & 15)];
      float xv[4] = { v.x, v.y, v.z, v.w };
      float dot = 0.f;
#pragma unroll
      for (int j = 0; j < 4; j++) dot += xv[j] * pwv[j];
      dot += __shfl_xor(dot, 1, 64);
      dot += __shfl_xor(dot, 2, 64);
      dot += __shfl_xor(dot, 4, 64);
      dot += __shfl_xor(dot, 8, 64);
      float cr = c[r];
#pragma unroll
      for (int j = 0; j < 4; j++) sacc[j] += cr * xv[j];
      if ((lane & 15) == 0) score[r] = dot * inv;
    }
#pragma unroll
    for (int j = 0; j < 4; j++) {
      sacc[j] += __shfl_xor(sacc[j], 16, 64);
      sacc[j] += __shfl_xor(sacc[j], 32, 64);
    }
    if (lane < 16) {
#pragma unroll
      for (int j = 0; j < 4; j++) sred[w][lane * 4 + j] = sacc[j];
    }
  }
  __syncthreads();
  if (w == 0)
    atomicAdd(&s8[(blockIdx.x & 7) * 64 + lane],
              sred[0][lane] + sred[1][lane] + sred[2][lane] + sred[3][lane]);
}

// ---- LDS-privatized full-resolution score histogram (proven R2) ----
__global__ void __launch_bounds__(1024) k_hist(const float* __restrict__ score,
                                               unsigned* __restrict__ part) {
  __shared__ unsigned lh[HW];
  int t = threadIdx.x;
  for (int k = t; k < HW; k += 1024) lh[k] = 0u;
  __syncthreads();
  int r0 = blockIdx.x * (NN / HB);
  int r1 = r0 + (NN / HB);
  for (int i = r0 + t; i < r1; i += 1024) {
    unsigned b = sortkey(score[i]) >> 16;
    atomicAdd(&lh[b >> 1], 1u << ((b & 1) * 16));
  }
  __syncthreads();
  unsigned* dst = part + (size_t)blockIdx.x * HW;
  for (int k = t; k < HW; k += 1024) dst[k] = lh[k];
}

// ---- sum HB packed partials -> hist (proven R2) ----
__global__ void k_redH(const unsigned* __restrict__ part, int* __restrict__ hist) {
  int w = blockIdx.x * 256 + threadIdx.x;
  unsigned lo = 0, hi = 0;
  for (int b = 0; b < HB; b++) {
    unsigned v = part[(size_t)b * HW + w];
    lo += v & 0xffffu;
    hi += v >> 16;
  }
  hist[2 * w]     = (int)lo;
  hist[2 * w + 1] = (int)hi;
}

// ---- threshold (proven) ----
__global__ void k_thresh(const int* __restrict__ hist, int* __restrict__ thrB,
                         const float* __restrict__ s8, float* __restrict__ svec) {
  __shared__ int part[256];
  __shared__ int segl[256];
  __shared__ int res2[2];
  int t = threadIdx.x, w = t >> 6, lane = t & 63;
  if (t < 64) {
    float a = 0.f;
    for (int r = 0; r < 8; r++) a += s8[r * 64 + t];
    svec[t] = a;
  }
  for (int m = w; m < 256; m += 4) {
    const int* hb = &hist[m * 256];
    int a = hb[lane] + hb[lane + 64] + hb[lane + 128] + hb[lane + 192];
    a = wsumi(a);
    if (lane == 0) part[m] = a;
  }
  __syncthreads();
  if (t == 0) {
    int acc = 0, seg = 0, above = 0;
    for (int b = 255; b >= 0; b--) {
      if (acc + part[b] >= 64) { seg = b; above = acc; break; }
      acc += part[b];
    }
    res2[0] = seg; res2[1] = above;
  }
  __syncthreads();
  segl[t] = hist[res2[0] * 256 + t];
  __syncthreads();
  if (t == 0) {
    int acc = res2[1], B = res2[0] * 256;
    for (int j = 255; j >= 0; j--) {
      acc += segl[j];
      if (acc >= 64) { B = res2[0] * 256 + j; break; }
    }
    thrB[0] = B;
  }
}

// ---- collect (proven) ----
__global__ void k_collect(const float* __restrict__ score, const int* __restrict__ thrB,
                          int* __restrict__ candn, unsigned* __restrict__ ckey,
                          int* __restrict__ cidx) {
  int i = blockIdx.x * blockDim.x + threadIdx.x;
  if (i >= NN) return;
  unsigned u = sortkey(score[i]);
  if ((int)(u >> 16) >= thrB[0]) {
    int p = atomicAdd(candn, 1);
    if (p < CAPL) { ckey[p] = u; cidx[p] = i; }
  }
}

// ---- top-64 (1024 threads, proven) ----
__global__ void __launch_bounds__(1024) k_top(const int* __restrict__ candn,
                      const unsigned* __restrict__ ckey,
                      const int* __restrict__ cidx, const void* x,
                      float* __restrict__ xt, const int* flagp) {
  __shared__ unsigned long long keys[CAPL];
  __shared__ int perm[64];
  __shared__ float ts[64];
  int flag = flagp[0];
  int t = threadIdx.x;
  int M = candn[0];
  if (M > CAPL) M = CAPL;
  for (int j = t; j < M; j += 1024)
    keys[j] = (((unsigned long long)ckey[j]) << 32) |
              (unsigned long long)(0xFFFFFFFFu - (unsigned)cidx[j]);
  __syncthreads();
  for (int j = t; j < M; j += 1024) {
    unsigned long long k = keys[j];
    int rank = 0;
    for (int i = 0; i < M; i++) rank += (keys[i] > k) ? 1 : 0;
    if (rank < 64) {
      unsigned ku = (unsigned)(k >> 32);
      unsigned idx = 0xFFFFFFFFu - (unsigned)(k & 0xFFFFFFFFu);
      perm[rank] = (int)idx;
      unsigned bits = (ku & 0x80000000u) ? (ku ^ 0x80000000u) : ~ku;
      ts[rank] = tanhf(__uint_as_float(bits));
    }
  }
  __syncthreads();
  for (int q = t; q < 4096; q += 1024) {
    int j = q >> 6, f = q & 63;
    xt[q] = ldf(x, perm[j] * 64 + f, flag) * ts[j];
  }
}

// ---- GRU (proven round-0 rework): coalesced staging, LDS-side transpose ----
#define GS 193
__device__ __forceinline__ void stage_w(const void* src, float* dst, int flag, int t) {
  if (flag) {
    const uint4* s4 = (const uint4*)src;
    for (int k = t; k < 1536; k += 256) {
      uint4 u = s4[k];
      int e = k << 3; int o = e >> 6, f = e & 63;
      float* d_ = &dst[f * GS + o];
      d_[0]      = bfu(u.x & 0xffff); d_[GS]     = bfu(u.x >> 16);
      d_[2 * GS] = bfu(u.y & 0xffff); d_[3 * GS] = bfu(u.y >> 16);
      d_[4 * GS] = bfu(u.z & 0xffff); d_[5 * GS] = bfu(u.z >> 16);
      d_[6 * GS] = bfu(u.w & 0xffff); d_[7 * GS] = bfu(u.w >> 16);
    }
  } else {
    const float4* s4 = (const float4*)src;
    for (int k = t; k < 3072; k += 256) {
      float4 v = s4[k];
      int e = k << 2; int o = e >> 6, f = e & 63;
      float* d_ = &dst[f * GS + o];
      d_[0] = v.x; d_[GS] = v.y; d_[2 * GS] = v.z; d_[3 * GS] = v.w;
    }
  }
}

__global__ void k_gru(const float* __restrict__ xt, const void* h0g, const void* wihg,
                      const void* whhg, const void* bihg, const void* bhhg,
                      float* __restrict__ Wout, const int* flagp) {
  __shared__ float wb1[64 * GS];
  __shared__ float wb2[64 * GS];
  __shared__ float xtr[256];
  __shared__ float h0r[256];
  int flag = flagp[0];
  int t = threadIdx.x;
  int j0 = blockIdx.x * 4;
  { int jj = t >> 6, f = t & 63;
    xtr[t] = xt[(j0 + jj) * 64 + f];
    h0r[t] = ldf(h0g, (j0 + jj) * 64 + f, flag); }
  stage_w(wihg, wb1, flag, t);
  stage_w(whhg, wb2, flag, t);
  __syncthreads();
  int jl = t >> 6, c2 = t & 63;
  float xr = 0, xz = 0, xn = 0, hr = 0, hz = 0, hn = 0;
#pragma unroll 4
  for (int f = 0; f < 64; f++) {
    float xv = xtr[jl * 64 + f];
    float hv = h0r[jl * 64 + f];
    const float* w1 = &wb1[f * GS];
    const float* w2 = &wb2[f * GS];
    xr += xv * w1[c2]; xz += xv * w1[64 + c2]; xn += xv * w1[128 + c2];
    hr += hv * w2[c2]; hz += hv * w2[64 + c2]; hn += hv * w2[128 + c2];
  }
  xr += ldf(bihg, c2, flag); xz += ldf(bihg, 64 + c2, flag); xn += ldf(bihg, 128 + c2, flag);
  hr += ldf(bhhg, c2, flag); hz += ldf(bhhg, 64 + c2, flag); hn += ldf(bhhg, 128 + c2, flag);
  float rg = 1.f / (1.f + expf(-(xr + hr)));
  float zg = 1.f / (1.f + expf(-(xz + hz)));
  float nc = tanhf(xn + rg * hn);
  Wout[(j0 + jl) * 64 + c2] = (1.f - zg) * nc + zg * h0r[jl * 64 + c2];
}

// ---- tail stage 1 (proven): 64 blocks spread weight reads ----
__global__ void k_g(const float* __restrict__ svec, const float* __restrict__ Wm,
                    const void* gw, const void* gb, float* __restrict__ g,
                    const int* flagp) {
  __shared__ float pooled[64];
  int flag = flagp[0];
  int t = threadIdx.x, w = t >> 6, lane = t & 63;
  if (t < 64) {
    float a = 0.f;
    for (int f = 0; f < 64; f++) a += svec[f] * Wm[f * 64 + t];
    pooled[t] = a * (1.0f / (float)NN);
  }
  __syncthreads();
  int o = blockIdx.x * 4 + w;
  float acc = pooled[lane] * ldf(gw, o * 64 + lane, flag);
  acc = wsum(acc);
  if (lane == 0) g[o] = acc + ldf(gb, o, flag);
}

// ---- tail stage 2 (proven) ----
__global__ void k_ln(const float* __restrict__ g, const float* __restrict__ d,
                     const void* lng, const void* lnb, float* __restrict__ lnv,
                     const int* flagp) {
  __shared__ float red[256];
  __shared__ float stats[2];
  int flag = flagp[0];
  int t = threadIdx.x;
  float v0 = g[t], v1 = d[t];
  red[t] = v0 + v1; __syncthreads();
  for (int s = 128; s > 0; s >>= 1) { if (t < s) red[t] += red[t + s]; __syncthreads(); }
  if (t == 0) stats[0] = red[0];
  __syncthreads();
  red[t] = v0 * v0 + v1 * v1; __syncthreads();
  for (int s = 128; s > 0; s >>= 1) { if (t < s) red[t] += red[t + s]; __syncthreads(); }
  if (t == 0) stats[1] = red[0];
  __syncthreads();
  float mu = stats[0] * (1.f / 512.f);
  float var = stats[1] * (1.f / 512.f) - mu * mu;
  float istd = rsqrtf(var + 1e-5f);
  lnv[t]       = (v0 - mu) * istd * ldf(lng, t, flag)       + ldf(lnb, t, flag);
  lnv[t + 256] = (v1 - mu) * istd * ldf(lng, t + 256, flag) + ldf(lnb, t + 256, flag);
}

// ---- tail stage 3 (proven) ----
__global__ void k_fuse(const float* __restrict__ lnv, const void* fw, const void* fb,
                       float* __restrict__ h1, const int* flagp) {
  __shared__ float lv[512];
  int flag = flagp[0];
  int t = threadIdx.x, w = t >> 6, lane = t & 63;
  lv[t] = lnv[t]; lv[t + 256] = lnv[t + 256];
  __syncthreads();
  int o = blockIdx.x * 4 + w;
  float acc = 0.f;
  if (flag) {
    uint4 u = *((const uint4*)((const unsigned short*)fw + o * 512) + lane);
    const float* l = &lv[lane * 8];
    acc = bfu(u.x & 0xffff) * l[0] + bfu(u.x >> 16) * l[1]
        + bfu(u.y & 0xffff) * l[2] + bfu(u.y >> 16) * l[3]
        + bfu(u.z & 0xffff) * l[4] + bfu(u.z >> 16) * l[5]
        + bfu(u.w & 0xffff) * l[6] + bfu(u.w >> 16) * l[7];
  } else {
    const float4* fv = (const float4*)((const float*)fw + o * 512);
    float4 a = fv[lane * 2], b = fv[lane * 2 + 1];
    const float* l = &lv[lane * 8];
    acc = a.x * l[0] + a.y * l[1] + a.z * l[2] + a.w * l[3]
        + b.x * l[4] + b.y * l[5] + b.z * l[6] + b.w * l[7];
  }
  acc = wsum(acc);
  if (lane == 0) h1[o] = fmaxf(acc + ldf(fb, o, flag), 0.0f);
}

// ---- tail stage 4 (proven) ----
__global__ void k_out(const float* __restrict__ h1, const void* tw, const void* tb,
                      const void* tmw, const void* tmb, void* out, const int* flagp) {
  int flag = flagp[0];
  int t = threadIdx.x, w = t >> 6, lane = t & 63;
  int o = blockIdx.x * 4 + w;
  if (o >= 17) return;
  float acc = 0.f;
  if (o < 16) { for (int k = lane; k < 256; k += 64) acc += h1[k] * ldf(tw, o * 256 + k, flag); }
  else        { for (int k = lane; k < 256; k += 64) acc += h1[k] * ldf(tmw, k, flag); }
  acc = wsum(acc);
  if (lane == 0) {
    float bias = (o < 16) ? ldf(tb, o, flag) : ldf(tmb, 0, flag);
    stf(out, o, acc + bias, flag);
  }
}

extern "C" void kernel_launch(void* const* d_in, const int* in_sizes, int n_in,
                              void* d_out, int out_size, void* d_ws, size_t ws_size,
                              hipStream_t stream) {
  const void* x    = d_in[0];
  const int*  ei   = (const int*)d_in[1];
  const void* docf = d_in[2];
  const void* pw   = d_in[3];
  const void* h0   = d_in[4];
  const void* wih  = d_in[5];
  const void* whh  = d_in[6];
  const void* bih  = d_in[7];
  const void* bhh  = d_in[8];
  const void* gw   = d_in[9];
  const void* gb   = d_in[10];
  const void* dw   = d_in[11];
  const void* db   = d_in[12];
  const void* lng  = d_in[13];
  const void* lnb  = d_in[14];
  const void* fw   = d_in[15];
  const void* fb   = d_in[16];
  const void* tw   = d_in[17];
  const void* tb   = d_in[18];
  const void* tmw  = d_in[19];
  const void* tmb  = d_in[20];

  const int* row = ei;
  const int* col = ei + EE;

  float* wsf = (float*)d_ws;
  int*   wsi = (int*)d_ws;

  int big = (ws_size >= (size_t)42 * 1024 * 1024);
  size_t base = big ? (size_t)BIGPART : (size_t)PARTW;

  size_t oHIST  = base;
  size_t oCANDN = oHIST + 65536;
  size_t oS8    = oCANDN + 8;
  size_t oFLAG  = oS8 + 512;
  size_t oTHR   = oFLAG + 8;
  size_t oSV    = oTHR + 8;
  size_t oD     = oSV + 64;
  size_t oDIS   = oD + 256;
  size_t oC     = oDIS + NN;
  size_t oSCORE = oC + NN;
  size_t oCKEY  = oSCORE + NN;
  size_t oCIDX  = oCKEY + 4096;
  size_t oXT    = oCIDX + 4096;
  size_t oWW    = oXT + 4096;
  size_t oG     = oWW + 4096;
  size_t oLNV   = oG + 256;
  size_t oH1    = oLNV + 512;

  hipMemsetAsync(wsi + oCANDN, 0, (size_t)(8 + 512) * 4, stream);
  k_detect<<<1, 256, 0, stream>>>((const unsigned short*)x, wsi + oFLAG);

  if (big) {
    k_hcolB<<<NBC3 * CCC3, HTH, 0, stream>>>(col, (unsigned*)wsi);
    k_redAB<<<NDBLK + 64, 256, 0, stream>>>((const unsigned*)wsi, wsf + oDIS,
                                            docf, dw, db, wsf + oD, wsi + oFLAG);
    k_hrowB<<<NBR2 * CCR2, HTH, 0, stream>>>(row, col, wsf + oDIS, wsf);
    k_redBB<<<NDBLK, 256, 0, stream>>>(wsf, wsf + oDIS, wsf + oC);
  } else {
    hipMemsetAsync(wsi, 0, (size_t)ZLEN1 * 4, stream);
    k_hcol<<<NBC * CCC, HTH, 0, stream>>>(col, (unsigned*)wsi);
    k_redA<<<NDBLK + 64, 256, 0, stream>>>((const unsigned*)wsi, wsf + oDIS,
                                           docf, dw, db, wsf + oD, wsi + oFLAG);
    hipMemsetAsync(wsi, 0, (size_t)ZLEN2 * 4, stream);
    k_hrow<<<NBR * CCR, HTH, 0, stream>>>(row, col, wsf + oDIS, wsf);
    k_redB<<<NDBLK, 256, 0, stream>>>(wsf, wsf + oDIS, wsf + oC);
  }

  k_x<<<XBLOCKS, 256, 0, stream>>>(x, pw, wsf + oC, wsf + oSCORE,
                                   wsf + oS8, wsi + oFLAG);
  k_hist<<<HB, 1024, 0, stream>>>(wsf + oSCORE, (unsigned*)wsi);
  k_redH<<<HW / 256, 256, 0, stream>>>((const unsigned*)wsi, wsi + oHIST);
  k_thresh<<<1, 256, 0, stream>>>(wsi + oHIST, wsi + oTHR, wsf + oS8, wsf + oSV);
  k_collect<<<NDBLK, 256, 0, stream>>>(wsf + oSCORE, wsi + oTHR, wsi + oCANDN,
                                       (unsigned*)(wsi + oCKEY), wsi + oCIDX);
  k_top<<<1, 1024, 0, stream>>>(wsi + oCANDN, (const unsigned*)(wsi + oCKEY),
                                wsi + oCIDX, x, wsf + oXT, wsi + oFLAG);
  k_gru<<<16, 256, 0, stream>>>(wsf + oXT, h0, wih, whh, bih, bhh, wsf + oWW, wsi + oFLAG);
  k_g<<<64, 256, 0, stream>>>(wsf + oSV, wsf + oWW, gw, gb, wsf + oG, wsi + oFLAG);
  k_ln<<<1, 256, 0, stream>>>(wsf + oG, wsf + oD, lng, lnb, wsf + oLNV, wsi + oFLAG);
  k_fuse<<<64, 256, 0, stream>>>(wsf + oLNV, fw, fb, wsf + oH1, wsi + oFLAG);
  k_out<<<5, 256, 0, stream>>>(wsf + oH1, tw, tb, tmw, tmb, d_out, wsi + oFLAG);
}